// Round 13
// baseline (480.549 us; speedup 1.0000x reference)
//
#include <hip/hip_runtime.h>
#include <stdint.h>

#define DEVFN __device__ __forceinline__

typedef unsigned short u16;
typedef unsigned int u32;

using f32x4 = __attribute__((ext_vector_type(4))) float;
using bfv8  = __attribute__((ext_vector_type(8))) short;   // 8 bf16 = 4 VGPR
using s16x4 = __attribute__((ext_vector_type(4))) short;   // 4 bf16 = 2 VGPR

#define CSC 0.12751745f   // (1/sqrt(128)) * log2(e)  -- folded into Q

DEVFN u16 f2bf(float f){
  u32 u = __float_as_uint(f);
  u32 r = u + 0x7FFFu + ((u >> 16) & 1u);
  return (u16)(r >> 16);
}
DEVFN float bf2f(u16 h){ return __uint_as_float(((u32)h) << 16); }

DEVFN void llds16(const void* g, void* l){
  __builtin_amdgcn_global_load_lds((const __attribute__((address_space(1))) void*)g,
                                   (__attribute__((address_space(3))) void*)l, 16, 0, 0);
}

DEVFN bfv8 as_bf(uint4 v){ return __builtin_bit_cast(bfv8, v); }

#if __has_builtin(__builtin_amdgcn_mfma_f32_16x16x16bf16_1k)
DEVFN f32x4 mfma16(s16x4 a, s16x4 b, f32x4 c){
  return __builtin_amdgcn_mfma_f32_16x16x16bf16_1k(a, b, c, 0, 0, 0);
}
#else
DEVFN f32x4 mfma16(s16x4 a, s16x4 b, f32x4 c){
  asm("v_mfma_f32_16x16x16_bf16 %0, %1, %2, %0" : "+v"(c) : "v"(a), "v"(b));
  return c;
}
#endif

DEVFN u32 cvtpk(float lo, float hi){
  u32 w;
  asm("v_cvt_pk_bf16_f32 %0, %1, %2" : "=v"(w) : "v"(lo), "v"(hi));
  return w;
}

// ---------------- cast hidden fp32 -> bf16 ----------------
__global__ __launch_bounds__(256) void cvt_hid_kernel(const float* __restrict__ src, u16* __restrict__ dst){
  int i = blockIdx.x * 256 + threadIdx.x;           // 8 elems per thread
  const float* s = src + (size_t)i * 8;
  float4 a = *(const float4*)s;
  float4 b = *(const float4*)(s + 4);
  u16 t[8] = {f2bf(a.x), f2bf(a.y), f2bf(a.z), f2bf(a.w),
              f2bf(b.x), f2bf(b.y), f2bf(b.z), f2bf(b.w)};
  *(uint4*)(dst + (size_t)i * 8) = *(const uint4*)t;
}

// ---------------- weights: fp32 [K][N] -> bf16 B^T [N][K] (K=4096) ----------------
__global__ __launch_bounds__(256) void wtrans_kernel(const float* __restrict__ qw, const float* __restrict__ kw,
                                                     const float* __restrict__ vw, const float* __restrict__ ow,
                                                     u16* __restrict__ wtall, u16* __restrict__ wto){
  __shared__ float tile[64 * 65];
  int z = blockIdx.x, tid = threadIdx.x;
  const float* W; u16* WT; int Ndim; int rz;
  if (z < 4096)      { W = qw; WT = wtall;                         Ndim = 4096; rz = z; }
  else if (z < 5120) { W = kw; WT = wtall + (size_t)4096 * 4096;   Ndim = 1024; rz = z - 4096; }
  else if (z < 6144) { W = vw; WT = wtall + (size_t)5120 * 4096;   Ndim = 1024; rz = z - 5120; }
  else               { W = ow; WT = wto;                           Ndim = 4096; rz = z - 6144; }
  int ntn = Ndim >> 6;
  int tk = rz / ntn, tn = rz % ntn;
  const float* src = W + (size_t)(tk * 64) * Ndim + tn * 64;
  #pragma unroll
  for (int it = 0; it < 4; ++it){
    int fi = tid + it * 256;          // float4 index (1024 total)
    int r = fi >> 4, c4 = (fi & 15) * 4;
    float4 v = *(const float4*)(src + (size_t)r * Ndim + c4);
    tile[r * 65 + c4 + 0] = v.x; tile[r * 65 + c4 + 1] = v.y;
    tile[r * 65 + c4 + 2] = v.z; tile[r * 65 + c4 + 3] = v.w;
  }
  __syncthreads();
  u16* dst = WT + (size_t)(tn * 64) * 4096 + tk * 64;
  #pragma unroll
  for (int it = 0; it < 2; ++it){
    int ci = tid + it * 256;          // chunk of 8 (512 total)
    int n = ci >> 3, k8 = (ci & 7) * 8;
    u16 tmp[8];
    #pragma unroll
    for (int j = 0; j < 8; ++j) tmp[j] = f2bf(tile[(k8 + j) * 65 + n]);
    *(uint4*)(dst + (size_t)n * 4096 + k8) = *(const uint4*)tmp;
  }
}

// ---------------- bf16 GEMM, 128x64 tile + XCD swizzle: C[M,N] = A[M,4096] * (BT[N,4096])^T ----------------
template<int OUTF32>
__global__ __launch_bounds__(256) void gemm_kernel(const u16* __restrict__ A, const u16* __restrict__ BT,
                                                   void* __restrict__ Cv, int N, int ntn){
  constexpr int K = 4096;
  __shared__ u16 As[2][128 * 32];
  __shared__ u16 Bs[2][64 * 32];
  int bid = blockIdx.x;
  {  // XCD-aware swizzle (T1): grid %8 == 0 for both call sites
    int cpx = gridDim.x >> 3;
    bid = (bid & 7) * cpx + (bid >> 3);
  }
  int bm = bid / ntn, bn = bid % ntn;
  int tid = threadIdx.x, lane = tid & 63, w = tid >> 6;
  int wr = w >> 1, wc = w & 1;
  int l15 = lane & 15, lh = lane >> 4;
  const u16* Ab = A  + (size_t)(bm * 128) * K;
  const u16* Bb = BT + (size_t)(bn * 64) * K;
  f32x4 acc[4][2];
  #pragma unroll
  for (int m = 0; m < 4; ++m)
    #pragma unroll
    for (int n = 0; n < 2; ++n) acc[m][n] = f32x4{0.f, 0.f, 0.f, 0.f};

  auto stage = [&](int buf, int k0){
    #pragma unroll
    for (int p = 0; p < 2; ++p){
      int cid = tid + p * 256;
      int row = cid >> 2, k8 = (cid & 3) * 8;
      llds16(Ab + (size_t)row * K + k0 + k8, (char*)(&As[buf][0]) + p * 4096 + w * 1024);
    }
    {
      int row = tid >> 2, k8 = (tid & 3) * 8;
      llds16(Bb + (size_t)row * K + k0 + k8, (char*)(&Bs[buf][0]) + w * 1024);
    }
  };
  stage(0, 0);
  __syncthreads();
  for (int kt = 0; kt < K / 32; ++kt){
    int cur = kt & 1;
    if (kt + 1 < K / 32) stage(cur ^ 1, (kt + 1) * 32);
    uint4 af[4], bfr[2];
    #pragma unroll
    for (int i = 0; i < 4; ++i)
      af[i]  = *(const uint4*)(&As[cur][(wr * 64 + i * 16 + l15) * 32 + lh * 8]);
    #pragma unroll
    for (int i = 0; i < 2; ++i)
      bfr[i] = *(const uint4*)(&Bs[cur][(wc * 32 + i * 16 + l15) * 32 + lh * 8]);
    #pragma unroll
    for (int m = 0; m < 4; ++m)
      #pragma unroll
      for (int n = 0; n < 2; ++n)
        acc[m][n] = __builtin_amdgcn_mfma_f32_16x16x32_bf16(as_bf(af[m]), as_bf(bfr[n]), acc[m][n], 0, 0, 0);
    __syncthreads();
  }
  int row0 = bm * 128 + wr * 64, col0 = bn * 64 + wc * 32;
  if (OUTF32){
    float* C = (float*)Cv;
    #pragma unroll
    for (int m = 0; m < 4; ++m)
      #pragma unroll
      for (int n = 0; n < 2; ++n)
        #pragma unroll
        for (int r = 0; r < 4; ++r)
          C[(size_t)(row0 + m * 16 + lh * 4 + r) * N + col0 + n * 16 + l15] = acc[m][n][r];
  } else {
    u16* C = (u16*)Cv;
    #pragma unroll
    for (int m = 0; m < 4; ++m)
      #pragma unroll
      for (int n = 0; n < 2; ++n)
        #pragma unroll
        for (int r = 0; r < 4; ++r)
          C[(size_t)(row0 + m * 16 + lh * 4 + r) * N + col0 + n * 16 + l15] = f2bf(acc[m][n][r]);
  }
}

// ---------------- RoPE: Q (scaled, SWIZZLED for LDS-Q path) -> qrope ; K -> knew fp32 ; V copy -> vnew fp32 ----------------
__global__ __launch_bounds__(256) void rope_kernel(const u16* __restrict__ qkvp, u16* __restrict__ qrope,
                                                   float* __restrict__ knew, float* __restrict__ vnew){
  int z = blockIdx.x, tid = threadIdx.x;
  if (z < 512){
    int b = z >> 5, h = z & 31;
    u16* dst = qrope + (size_t)((b * 32 + h) * 64) * 128;
    for (int it = 0; it < 16; ++it){
      int i = tid + it * 256;
      int s = i >> 6, j = i & 63;
      const u16* src = qkvp + (size_t)(b * 64 + s) * 6144 + h * 128;
      float q0 = bf2f(src[j]), q1 = bf2f(src[j + 64]);
      float inv = expf(-(float)j * 0.14391157f);      // 1/10000^(j/64)
      float ang = (4032.0f + (float)s) * inv;
      float sn = sinf(ang), cs = cosf(ang);
      // swizzled store: elem (q=s, d) at q*128 + ((dc&8)|((dc^q)&7))*8 + (d&7)
      int dcs = ((j >> 3) ^ s) & 7;
      dst[s * 128 + dcs * 8 + (j & 7)]      = f2bf((q0 * cs - q1 * sn) * CSC);
      dst[s * 128 + 64 + dcs * 8 + (j & 7)] = f2bf((q1 * cs + q0 * sn) * CSC);
    }
  } else {
    int z2 = z - 512, b = z2 >> 3, kvh = z2 & 7;
    for (int it = 0; it < 16; ++it){
      int i = tid + it * 256;
      int s = i >> 6, j = i & 63;
      const u16* src = qkvp + (size_t)(b * 64 + s) * 6144 + 4096 + kvh * 128;
      float q0 = bf2f(src[j]), q1 = bf2f(src[j + 64]);
      float inv = expf(-(float)j * 0.14391157f);
      float ang = (4032.0f + (float)s) * inv;
      float sn = sinf(ang), cs = cosf(ang);
      float* kd = knew + ((size_t)(b * 8 + kvh) * 64 + s) * 128;
      kd[j]      = q0 * cs - q1 * sn;
      kd[j + 64] = q1 * cs + q0 * sn;
      const u16* vs = qkvp + (size_t)(b * 64 + s) * 6144 + 5120 + kvh * 128;
      float* vd = vnew + ((size_t)(b * 8 + kvh) * 64 + s) * 128;
      vd[j]      = bf2f(vs[j]);
      vd[j + 64] = bf2f(vs[j + 64]);
    }
  }
}

// ---------------- flash attention (r9 skeleton, 64-t phases: 2 sub-tiles per barrier) ----------------
// block: 512 thr = 4 consumer waves (one head each, Q in per-wave LDS) + 4 producer waves
// 2 T-chunks of 2048 -> grid 256 blocks = 1/CU, 32 phases x 64 t (2x 32-t sub-tiles, swizzles unchanged)
__global__ __launch_bounds__(512, 2) void attn_kernel(const u16* __restrict__ qrope, const float* __restrict__ pastk,
                                                      const float* __restrict__ pastv, const float* __restrict__ knew,
                                                      const float* __restrict__ vnew, const int* __restrict__ beam,
                                                      float* __restrict__ pctx, float* __restrict__ pm,
                                                      float* __restrict__ pl){
  __shared__ u16 Qs[4][8192];      // per consumer wave: [64 q][128 d], chunk-swizzled (pre-swizzled in qrope)
  __shared__ u16 Ks[2][2][4096];   // [buf][sub][32 t][128 d], chunk swz (dc&8)|((dc^t)&7)
  __shared__ u16 Vs[2][2][4608];   // [buf][sub][128 d][stride 36], t-quad slot = q ^ swz2(d) ^ (d>>5)
  int kv = blockIdx.x, b = blockIdx.y, chunk = blockIdx.z;
  int tid = threadIdx.x, lane = tid & 63, w = tid >> 6;
  int l15 = lane & 15, lh = lane >> 4;
  constexpr int NP = 32;           // phases of 64 t

  if (w >= 4){
    // ================= producer (single reg set, depth-1 phase prefetch) =================
    int p = w - 4;
    int dblk = l15;               // 8-d block
    int tq = p * 8 + lh * 2;      // sub-tile-local t (even); stages rows tq, tq+1
    int bmb = beam[b];
    const float* kpast = pastk + (size_t)(bmb * 8 + kv) * 4032 * 128;
    const float* vpast = pastv + (size_t)(bmb * 8 + kv) * 4032 * 128;
    const float* knb = knew + (size_t)(b * 8 + kv) * 64 * 128;
    const float* vnb = vnew + (size_t)(b * 8 + kv) * 64 * 128;

    auto loadSub = [&](int tix, float4* rk, float4* rv){   // tix = global 32-t tile index
      int tg0 = chunk * 2048 + tix * 32;
      const float *ksrc, *vsrc;
      if (tg0 >= 4032){ ksrc = knb + (size_t)(tg0 - 4032) * 128; vsrc = vnb + (size_t)(tg0 - 4032) * 128; }
      else            { ksrc = kpast + (size_t)tg0 * 128;         vsrc = vpast + (size_t)tg0 * 128; }
      const float* k0 = ksrc + (size_t)tq * 128 + dblk * 8;
      const float* k1 = ksrc + (size_t)(tq + 1) * 128 + dblk * 8;
      const float* v0 = vsrc + (size_t)tq * 128 + dblk * 8;
      const float* v1 = vsrc + (size_t)(tq + 1) * 128 + dblk * 8;
      rk[0] = *(const float4*)k0; rk[1] = *(const float4*)(k0 + 4);
      rk[2] = *(const float4*)k1; rk[3] = *(const float4*)(k1 + 4);
      rv[0] = *(const float4*)v0; rv[1] = *(const float4*)(v0 + 4);
      rv[2] = *(const float4*)v1; rv[3] = *(const float4*)(v1 + 4);
    };
    auto writeSub = [&](int buf, int sub, const float4* rk, const float4* rv){
      uint4 pk0, pk1;
      pk0.x = cvtpk(rk[0].x, rk[0].y); pk0.y = cvtpk(rk[0].z, rk[0].w);
      pk0.z = cvtpk(rk[1].x, rk[1].y); pk0.w = cvtpk(rk[1].z, rk[1].w);
      pk1.x = cvtpk(rk[2].x, rk[2].y); pk1.y = cvtpk(rk[2].z, rk[2].w);
      pk1.z = cvtpk(rk[3].x, rk[3].y); pk1.w = cvtpk(rk[3].z, rk[3].w);
      int dcs0 = (dblk & 8) | ((dblk ^ tq) & 7);
      int dcs1 = (dblk & 8) | ((dblk ^ (tq + 1)) & 7);
      *(uint4*)(&Ks[buf][sub][tq * 128 + dcs0 * 8])       = pk0;
      *(uint4*)(&Ks[buf][sub][(tq + 1) * 128 + dcs1 * 8]) = pk1;
      float va[8] = {rv[0].x, rv[0].y, rv[0].z, rv[0].w, rv[1].x, rv[1].y, rv[1].z, rv[1].w};
      float vb[8] = {rv[2].x, rv[2].y, rv[2].z, rv[2].w, rv[3].x, rv[3].y, rv[3].z, rv[3].w};
      #pragma unroll
      for (int dd = 0; dd < 8; ++dd){
        int d = dblk * 8 + dd;
        int cc = (p ^ ((dblk ^ dd) & 3) ^ (dblk >> 2)) & 3;
        *(u32*)(&Vs[buf][sub][d * 36 + cc * 8 + lh * 2]) = cvtpk(va[dd], vb[dd]);
      }
    };

    float4 rk0[4], rv0[4], rk1[4], rv1[4];   // one phase (2 subs) in flight
    loadSub(0, rk0, rv0); loadSub(1, rk1, rv1);
    asm volatile("s_waitcnt vmcnt(0)" ::: "memory");
    writeSub(0, 0, rk0, rv0); writeSub(0, 1, rk1, rv1);
    loadSub(2, rk0, rv0); loadSub(3, rk1, rv1);        // phase 1
    asm volatile("s_waitcnt lgkmcnt(0)" ::: "memory");
    __builtin_amdgcn_sched_barrier(0);
    __builtin_amdgcn_s_barrier();
    __builtin_amdgcn_sched_barrier(0);
    for (int it = 0; it < NP; ++it){
      // consumer computes buf it&1; producer stages phase it+1 -> buf (it+1)&1, prefetches phase it+2
      if (it + 1 < NP){
        asm volatile("s_waitcnt vmcnt(0)" ::: "memory");
        writeSub((it + 1) & 1, 0, rk0, rv0);
        writeSub((it + 1) & 1, 1, rk1, rv1);
        if (it + 2 < NP){
          loadSub((it + 2) * 2,     rk0, rv0);
          loadSub((it + 2) * 2 + 1, rk1, rv1);
        }
        asm volatile("s_waitcnt lgkmcnt(0)" ::: "memory");
      }
      __builtin_amdgcn_sched_barrier(0);
      __builtin_amdgcn_s_barrier();
      __builtin_amdgcn_sched_barrier(0);
    }
    return;
  }

  // ================= consumer =================
  // stage own Q (pre-swizzled in qrope -> linear copy keeps swizzle)
  const u16* qb = qrope + (size_t)((b * 32 + kv * 4 + w) * 64) * 128;
  #pragma unroll
  for (int c = 0; c < 16; ++c)
    llds16((const char*)qb + c * 1024 + lane * 16, (char*)(&Qs[w][0]) + c * 1024);
  asm volatile("s_waitcnt vmcnt(0)" ::: "memory");

  f32x4 cacc[8][4];             // [nd][qm]: ctx^T rows d=nd*16+lh*4+r, cols q=qm*16+l15
  float mrow[4], lrow[4];
  #pragma unroll
  for (int qm = 0; qm < 4; ++qm){ mrow[qm] = -3.0e38f; lrow[qm] = 0.f; }
  #pragma unroll
  for (int nd = 0; nd < 8; ++nd)
    #pragma unroll
    for (int qm = 0; qm < 4; ++qm) cacc[nd][qm] = f32x4{0.f, 0.f, 0.f, 0.f};

  __builtin_amdgcn_sched_barrier(0);
  __builtin_amdgcn_s_barrier();
  __builtin_amdgcn_sched_barrier(0);

  for (int it = 0; it < NP; ++it){
    #pragma unroll
    for (int sub = 0; sub < 2; ++sub){
      const u16* Kc = &Ks[it & 1][sub][0];
      const u16* Vc = &Vs[it & 1][sub][0];
      int gtile = it * 2 + sub;

      // S^T = K * Q^T : sacc[tt][qm] rows t=tt*16+lh*4+r, cols q=qm*16+l15
      f32x4 sacc[2][4];
      #pragma unroll
      for (int tt = 0; tt < 2; ++tt)
        #pragma unroll
        for (int qm = 0; qm < 4; ++qm) sacc[tt][qm] = f32x4{0.f, 0.f, 0.f, 0.f};
      #pragma unroll
      for (int ks = 0; ks < 4; ++ks){
        int dc = ks * 4 + lh;
        int dcs = (dc & 8) | ((dc ^ l15) & 7);
        uint4 kf0 = *(const uint4*)(Kc + l15 * 128 + dcs * 8);
        uint4 kf1 = *(const uint4*)(Kc + (16 + l15) * 128 + dcs * 8);
        #pragma unroll
        for (int qm = 0; qm < 4; ++qm){
          uint4 qf = *(const uint4*)(&Qs[w][(qm * 16 + l15) * 128 + dcs * 8]);
          sacc[0][qm] = __builtin_amdgcn_mfma_f32_16x16x32_bf16(as_bf(kf0), as_bf(qf), sacc[0][qm], 0, 0, 0);
          sacc[1][qm] = __builtin_amdgcn_mfma_f32_16x16x32_bf16(as_bf(kf1), as_bf(qf), sacc[1][qm], 0, 0, 0);
        }
      }

      // causal mask: only last two 32-t tiles of chunk 1 (new tokens start at t=4032)
      if (chunk == 1 && gtile >= 62){
        int toff = (gtile - 62) * 32;
        #pragma unroll
        for (int tt = 0; tt < 2; ++tt)
          #pragma unroll
          for (int qm = 0; qm < 4; ++qm)
            #pragma unroll
            for (int r = 0; r < 4; ++r){
              int t = toff + tt * 16 + lh * 4 + r;
              int q = qm * 16 + l15;
              if (t > q) sacc[tt][qm][r] = -3.0e38f;
            }
      }

      // lazy online softmax: lane-local max check; full reduce+rescale only on trigger;
      // l kept as lane-local partial (sum is linear) and reduced once after the loop.
      #pragma unroll
      for (int qm = 0; qm < 4; ++qm){
        float rm = sacc[0][qm][0];
        #pragma unroll
        for (int tt = 0; tt < 2; ++tt)
          #pragma unroll
          for (int r = 0; r < 4; ++r) rm = fmaxf(rm, sacc[tt][qm][r]);
        if (__any(rm > mrow[qm] + 8.0f)){          // defer-max (log2 units)
          rm = fmaxf(rm, __shfl_xor(rm, 16));
          rm = fmaxf(rm, __shfl_xor(rm, 32));
          float mn = fmaxf(mrow[qm], rm);
          float esc = exp2f(mrow[qm] - mn);
          mrow[qm] = mn;
          lrow[qm] *= esc;
          #pragma unroll
          for (int nd = 0; nd < 8; ++nd) cacc[nd][qm] *= esc;
        }
        float s = 0.f;
        #pragma unroll
        for (int tt = 0; tt < 2; ++tt)
          #pragma unroll
          for (int r = 0; r < 4; ++r){
            float pp = exp2f(sacc[tt][qm][r] - mrow[qm]);
            sacc[tt][qm][r] = pp;
            s += pp;
          }
        lrow[qm] += s;                             // lane-local partial
      }

      // ctx^T += V^T * P^T via 16x16x16 MFMA (P in registers)
      #pragma unroll
      for (int tt = 0; tt < 2; ++tt){
        s16x4 pa[4];
        #pragma unroll
        for (int qm = 0; qm < 4; ++qm){
          uint2 u;
          u.x = cvtpk(sacc[tt][qm][0], sacc[tt][qm][1]);
          u.y = cvtpk(sacc[tt][qm][2], sacc[tt][qm][3]);
          pa[qm] = __builtin_bit_cast(s16x4, u);
        }
        #pragma unroll
        for (int nd = 0; nd < 8; ++nd){
          int swzv = ((nd * 2) ^ (l15 >> 3) ^ l15) & 3;          // ((d>>3)^d)&3
          int cc = ((tt * 2 + (lh >> 1)) ^ swzv ^ (nd >> 1)) & 3;
          uint2 vr = *(const uint2*)(Vc + (nd * 16 + l15) * 36 + cc * 8 + (lh & 1) * 4);
          s16x4 vfr = __builtin_bit_cast(s16x4, vr);
          #pragma unroll
          for (int qm = 0; qm < 4; ++qm)
            cacc[nd][qm] = mfma16(vfr, pa[qm], cacc[nd][qm]);
        }
      }
    }
    __builtin_amdgcn_sched_barrier(0);
    __builtin_amdgcn_s_barrier();
    __builtin_amdgcn_sched_barrier(0);
  }

  // reduce lane-local l partials across the 4 lh replicas of each q
  #pragma unroll
  for (int qm = 0; qm < 4; ++qm){
    lrow[qm] += __shfl_xor(lrow[qm], 16);
    lrow[qm] += __shfl_xor(lrow[qm], 32);
  }

  // unnormalized partials (contiguous stores) + (m,l)
  float* pc = pctx + (size_t)(((chunk * 16 + b) * 8 + kv) * 4 + w) * 8192;
  #pragma unroll
  for (int qm = 0; qm < 4; ++qm){
    int q = qm * 16 + l15;
    #pragma unroll
    for (int nd = 0; nd < 8; ++nd)
      *(f32x4*)(pc + (size_t)q * 128 + nd * 16 + lh * 4) = cacc[nd][qm];
  }
  if (lh == 0){
    size_t mb = (size_t)((chunk * 16 + b) * 8 + kv) * 256 + w * 64;
    #pragma unroll
    for (int qm = 0; qm < 4; ++qm){
      pm[mb + qm * 16 + l15] = mrow[qm];
      pl[mb + qm * 16 + l15] = lrow[qm];
    }
  }
}

// ---------------- combine the 2 chunk partials ----------------
__global__ __launch_bounds__(256) void combine_kernel(const float* __restrict__ pctx, const float* __restrict__ pm,
                                                      const float* __restrict__ pl, u16* __restrict__ ctxb){
  int z = blockIdx.x;
  int g = z & 3, kv = (z >> 2) & 7, b = z >> 5;
  int tid = threadIdx.x;
  int s = tid >> 2, dq = (tid & 3) * 32;
  float mv[2], lv[2];
  #pragma unroll
  for (int c = 0; c < 2; ++c){
    size_t mi = (size_t)((c * 16 + b) * 8 + kv) * 256 + g * 64 + s;
    mv[c] = pm[mi]; lv[c] = pl[mi];
  }
  float M = fmaxf(mv[0], mv[1]);
  float wc[2], wsum = 0.f;
  #pragma unroll
  for (int c = 0; c < 2; ++c){ wc[c] = exp2f(mv[c] - M); wsum += wc[c] * lv[c]; }
  float inv = 1.0f / wsum;
  u16* dst = ctxb + (size_t)(b * 64 + s) * 4096 + (kv * 4 + g) * 128 + dq;
  #pragma unroll
  for (int j4 = 0; j4 < 8; ++j4){
    float4 a = {0.f, 0.f, 0.f, 0.f};
    #pragma unroll
    for (int c = 0; c < 2; ++c){
      const float* p = pctx + (size_t)(((c * 16 + b) * 8 + kv) * 4 + g) * 8192 + s * 128 + dq + j4 * 4;
      float4 v = *(const float4*)p;
      a.x += wc[c] * v.x; a.y += wc[c] * v.y; a.z += wc[c] * v.z; a.w += wc[c] * v.w;
    }
    u16 t4[4] = {f2bf(a.x * inv), f2bf(a.y * inv), f2bf(a.z * inv), f2bf(a.w * inv)};
    *(uint2*)(dst + j4 * 4) = *(const uint2*)t4;
  }
}

extern "C" void kernel_launch(void* const* d_in, const int* in_sizes, int n_in,
                              void* d_out, int out_size, void* d_ws, size_t ws_size,
                              hipStream_t stream){
  const float* hidden = (const float*)d_in[0];
  const float* pastk  = (const float*)d_in[1];
  const float* pastv  = (const float*)d_in[2];
  const float* qw     = (const float*)d_in[3];
  const float* kw     = (const float*)d_in[4];
  const float* vw     = (const float*)d_in[5];
  const float* ow     = (const float*)d_in[6];
  const int*   beam   = (const int*)d_in[7];

  char* ws = (char*)d_ws;
  size_t off = 0;
  auto alloc = [&](size_t sz){ char* p = ws + off; off += sz; return p; };
  u16*   wtall = (u16*)alloc(50331648);     // [6144][4096] bf16: q,k,v weights transposed
  u16*   wto   = (u16*)alloc(33554432);     // [4096][4096] bf16: out_wei transposed
  u16*   hidb  = (u16*)alloc(8388608);      // hidden bf16 [1024][4096]
  u16*   qkvp  = (u16*)alloc(12582912);     // QKV proj [1024][6144]
  u16*   qrope = (u16*)alloc(8388608);      // [16][32][64][128] swizzled
  float* knew  = (float*)alloc(4194304);    // [16][8][64][128] fp32 roped new K
  float* vnew  = (float*)alloc(4194304);    // [16][8][64][128] fp32 new V
  float* pctx  = (float*)alloc(33554432);   // [2][16][8][4][64][128]
  float* pm    = (float*)alloc(262144);
  float* pl    = (float*)alloc(262144);
  u16*   ctxb  = (u16*)alloc(8388608);      // [1024][4096]
  if (off > ws_size) return;                // workspace too small -> fail loudly

  cvt_hid_kernel<<<2048, 256, 0, stream>>>(hidden, hidb);
  wtrans_kernel<<<10240, 256, 0, stream>>>(qw, kw, vw, ow, wtall, wto);
  gemm_kernel<0><<<768, 256, 0, stream>>>(hidb, wtall, (void*)qkvp, 6144, 96);
  rope_kernel<<<640, 256, 0, stream>>>(qkvp, qrope, knew, vnew);
  attn_kernel<<<dim3(8, 16, 2), 512, 0, stream>>>(qrope, pastk, pastv, knew, vnew, beam, pctx, pm, pl);
  combine_kernel<<<512, 256, 0, stream>>>(pctx, pm, pl, ctxb);
  gemm_kernel<1><<<512, 256, 0, stream>>>(ctxb, wto, d_out, 4096, 64);
}

// Round 14
// 390.888 us; speedup vs baseline: 1.2294x; 1.2294x over previous
//
#include <hip/hip_runtime.h>
#include <stdint.h>

#define DEVFN __device__ __forceinline__

typedef unsigned short u16;
typedef unsigned int u32;

using f32x4 = __attribute__((ext_vector_type(4))) float;
using bfv8  = __attribute__((ext_vector_type(8))) short;   // 8 bf16 = 4 VGPR
using s16x4 = __attribute__((ext_vector_type(4))) short;   // 4 bf16 = 2 VGPR

#define CSC 0.12751745f   // (1/sqrt(128)) * log2(e)  -- folded into Q

DEVFN u16 f2bf(float f){
  u32 u = __float_as_uint(f);
  u32 r = u + 0x7FFFu + ((u >> 16) & 1u);
  return (u16)(r >> 16);
}
DEVFN float bf2f(u16 h){ return __uint_as_float(((u32)h) << 16); }

DEVFN void llds16(const void* g, void* l){
  __builtin_amdgcn_global_load_lds((const __attribute__((address_space(1))) void*)g,
                                   (__attribute__((address_space(3))) void*)l, 16, 0, 0);
}

DEVFN bfv8 as_bf(uint4 v){ return __builtin_bit_cast(bfv8, v); }

#if __has_builtin(__builtin_amdgcn_mfma_f32_16x16x16bf16_1k)
DEVFN f32x4 mfma16(s16x4 a, s16x4 b, f32x4 c){
  return __builtin_amdgcn_mfma_f32_16x16x16bf16_1k(a, b, c, 0, 0, 0);
}
#else
DEVFN f32x4 mfma16(s16x4 a, s16x4 b, f32x4 c){
  asm("v_mfma_f32_16x16x16_bf16 %0, %1, %2, %0" : "+v"(c) : "v"(a), "v"(b));
  return c;
}
#endif

DEVFN u32 cvtpk(float lo, float hi){
  u32 w;
  asm("v_cvt_pk_bf16_f32 %0, %1, %2" : "=v"(w) : "v"(lo), "v"(hi));
  return w;
}

// ---------------- cast hidden fp32 -> bf16 ----------------
__global__ __launch_bounds__(256) void cvt_hid_kernel(const float* __restrict__ src, u16* __restrict__ dst){
  int i = blockIdx.x * 256 + threadIdx.x;           // 8 elems per thread
  const float* s = src + (size_t)i * 8;
  float4 a = *(const float4*)s;
  float4 b = *(const float4*)(s + 4);
  u16 t[8] = {f2bf(a.x), f2bf(a.y), f2bf(a.z), f2bf(a.w),
              f2bf(b.x), f2bf(b.y), f2bf(b.z), f2bf(b.w)};
  *(uint4*)(dst + (size_t)i * 8) = *(const uint4*)t;
}

// ---------------- trig table: [64 s][64 j] (cos, sin) ----------------
__global__ __launch_bounds__(256) void trig_kernel(float2* __restrict__ tbl){
  int i = blockIdx.x * 256 + threadIdx.x;   // 4096 entries
  int s = i >> 6, j = i & 63;
  float inv = expf(-(float)j * 0.14391157f);   // 1/10000^(j/64)
  float ang = (4032.0f + (float)s) * inv;
  tbl[i] = make_float2(cosf(ang), sinf(ang));
}

// ---------------- weights: fp32 [K][N] -> bf16 B^T [N][K] (K=4096) ----------------
__global__ __launch_bounds__(256) void wtrans_kernel(const float* __restrict__ qw, const float* __restrict__ kw,
                                                     const float* __restrict__ vw, const float* __restrict__ ow,
                                                     u16* __restrict__ wtall, u16* __restrict__ wto){
  __shared__ float tile[64 * 65];
  int z = blockIdx.x, tid = threadIdx.x;
  const float* W; u16* WT; int Ndim; int rz;
  if (z < 4096)      { W = qw; WT = wtall;                         Ndim = 4096; rz = z; }
  else if (z < 5120) { W = kw; WT = wtall + (size_t)4096 * 4096;   Ndim = 1024; rz = z - 4096; }
  else if (z < 6144) { W = vw; WT = wtall + (size_t)5120 * 4096;   Ndim = 1024; rz = z - 5120; }
  else               { W = ow; WT = wto;                           Ndim = 4096; rz = z - 6144; }
  int ntn = Ndim >> 6;
  int tk = rz / ntn, tn = rz % ntn;
  const float* src = W + (size_t)(tk * 64) * Ndim + tn * 64;
  #pragma unroll
  for (int it = 0; it < 4; ++it){
    int fi = tid + it * 256;          // float4 index (1024 total)
    int r = fi >> 4, c4 = (fi & 15) * 4;
    float4 v = *(const float4*)(src + (size_t)r * Ndim + c4);
    tile[r * 65 + c4 + 0] = v.x; tile[r * 65 + c4 + 1] = v.y;
    tile[r * 65 + c4 + 2] = v.z; tile[r * 65 + c4 + 3] = v.w;
  }
  __syncthreads();
  u16* dst = WT + (size_t)(tn * 64) * 4096 + tk * 64;
  #pragma unroll
  for (int it = 0; it < 2; ++it){
    int ci = tid + it * 256;          // chunk of 8 (512 total)
    int n = ci >> 3, k8 = (ci & 7) * 8;
    u16 tmp[8];
    #pragma unroll
    for (int j = 0; j < 8; ++j) tmp[j] = f2bf(tile[(k8 + j) * 65 + n]);
    *(uint4*)(dst + (size_t)n * 4096 + k8) = *(const uint4*)tmp;
  }
}

// ---------------- bf16 GEMM, 128x64 tile + XCD swizzle: C[M,N] = A[M,4096] * (BT[N,4096])^T ----------------
template<int OUTF32>
__global__ __launch_bounds__(256) void gemm_kernel(const u16* __restrict__ A, const u16* __restrict__ BT,
                                                   void* __restrict__ Cv, int N, int ntn){
  constexpr int K = 4096;
  __shared__ u16 As[2][128 * 32];
  __shared__ u16 Bs[2][64 * 32];
  int bid = blockIdx.x;
  {  // XCD-aware swizzle (T1): grid %8 == 0 for both call sites
    int cpx = gridDim.x >> 3;
    bid = (bid & 7) * cpx + (bid >> 3);
  }
  int bm = bid / ntn, bn = bid % ntn;
  int tid = threadIdx.x, lane = tid & 63, w = tid >> 6;
  int wr = w >> 1, wc = w & 1;
  int l15 = lane & 15, lh = lane >> 4;
  const u16* Ab = A  + (size_t)(bm * 128) * K;
  const u16* Bb = BT + (size_t)(bn * 64) * K;
  f32x4 acc[4][2];
  #pragma unroll
  for (int m = 0; m < 4; ++m)
    #pragma unroll
    for (int n = 0; n < 2; ++n) acc[m][n] = f32x4{0.f, 0.f, 0.f, 0.f};

  auto stage = [&](int buf, int k0){
    #pragma unroll
    for (int p = 0; p < 2; ++p){
      int cid = tid + p * 256;
      int row = cid >> 2, k8 = (cid & 3) * 8;
      llds16(Ab + (size_t)row * K + k0 + k8, (char*)(&As[buf][0]) + p * 4096 + w * 1024);
    }
    {
      int row = tid >> 2, k8 = (tid & 3) * 8;
      llds16(Bb + (size_t)row * K + k0 + k8, (char*)(&Bs[buf][0]) + w * 1024);
    }
  };
  stage(0, 0);
  __syncthreads();
  for (int kt = 0; kt < K / 32; ++kt){
    int cur = kt & 1;
    if (kt + 1 < K / 32) stage(cur ^ 1, (kt + 1) * 32);
    uint4 af[4], bfr[2];
    #pragma unroll
    for (int i = 0; i < 4; ++i)
      af[i]  = *(const uint4*)(&As[cur][(wr * 64 + i * 16 + l15) * 32 + lh * 8]);
    #pragma unroll
    for (int i = 0; i < 2; ++i)
      bfr[i] = *(const uint4*)(&Bs[cur][(wc * 32 + i * 16 + l15) * 32 + lh * 8]);
    #pragma unroll
    for (int m = 0; m < 4; ++m)
      #pragma unroll
      for (int n = 0; n < 2; ++n)
        acc[m][n] = __builtin_amdgcn_mfma_f32_16x16x32_bf16(as_bf(af[m]), as_bf(bfr[n]), acc[m][n], 0, 0, 0);
    __syncthreads();
  }
  int row0 = bm * 128 + wr * 64, col0 = bn * 64 + wc * 32;
  if (OUTF32){
    float* C = (float*)Cv;
    #pragma unroll
    for (int m = 0; m < 4; ++m)
      #pragma unroll
      for (int n = 0; n < 2; ++n)
        #pragma unroll
        for (int r = 0; r < 4; ++r)
          C[(size_t)(row0 + m * 16 + lh * 4 + r) * N + col0 + n * 16 + l15] = acc[m][n][r];
  } else {
    u16* C = (u16*)Cv;
    #pragma unroll
    for (int m = 0; m < 4; ++m)
      #pragma unroll
      for (int n = 0; n < 2; ++n)
        #pragma unroll
        for (int r = 0; r < 4; ++r)
          C[(size_t)(row0 + m * 16 + lh * 4 + r) * N + col0 + n * 16 + l15] = f2bf(acc[m][n][r]);
  }
}

// ---------------- RoPE (table-driven): Q (scaled, SWIZZLED) -> qrope ; K -> knew fp32 ; V copy -> vnew ----------------
__global__ __launch_bounds__(256) void rope_kernel(const u16* __restrict__ qkvp, const float2* __restrict__ tbl,
                                                   u16* __restrict__ qrope, float* __restrict__ knew,
                                                   float* __restrict__ vnew){
  int z = blockIdx.x, tid = threadIdx.x;
  if (z < 512){
    int b = z >> 5, h = z & 31;
    u16* dst = qrope + (size_t)((b * 32 + h) * 64) * 128;
    for (int it = 0; it < 16; ++it){
      int i = tid + it * 256;
      int s = i >> 6, j = i & 63;
      const u16* src = qkvp + (size_t)(b * 64 + s) * 6144 + h * 128;
      float q0 = bf2f(src[j]), q1 = bf2f(src[j + 64]);
      float2 t = tbl[i];
      float cs = t.x, sn = t.y;
      // swizzled store: elem (q=s, d) at q*128 + ((dc&8)|((dc^q)&7))*8 + (d&7)
      int dcs = ((j >> 3) ^ s) & 7;
      dst[s * 128 + dcs * 8 + (j & 7)]      = f2bf((q0 * cs - q1 * sn) * CSC);
      dst[s * 128 + 64 + dcs * 8 + (j & 7)] = f2bf((q1 * cs + q0 * sn) * CSC);
    }
  } else {
    int z2 = z - 512, b = z2 >> 3, kvh = z2 & 7;
    for (int it = 0; it < 16; ++it){
      int i = tid + it * 256;
      int s = i >> 6, j = i & 63;
      const u16* src = qkvp + (size_t)(b * 64 + s) * 6144 + 4096 + kvh * 128;
      float q0 = bf2f(src[j]), q1 = bf2f(src[j + 64]);
      float2 t = tbl[i];
      float cs = t.x, sn = t.y;
      float* kd = knew + ((size_t)(b * 8 + kvh) * 64 + s) * 128;
      kd[j]      = q0 * cs - q1 * sn;
      kd[j + 64] = q1 * cs + q0 * sn;
      const u16* vs = qkvp + (size_t)(b * 64 + s) * 6144 + 5120 + kvh * 128;
      float* vd = vnew + ((size_t)(b * 8 + kvh) * 64 + s) * 128;
      vd[j]      = bf2f(vs[j]);
      vd[j + 64] = bf2f(vs[j + 64]);
    }
  }
}

// ---------------- flash attention (r9/r12 verbatim + T5 setprio on consumer MFMA clusters) ----------------
// block: 512 thr = 4 consumer waves (one head each, Q in per-wave LDS) + 4 producer waves
// 2 T-chunks of 2048 -> grid 256 blocks = 1/CU, NT=64 tiles of 32 t
__global__ __launch_bounds__(512, 2) void attn_kernel(const u16* __restrict__ qrope, const float* __restrict__ pastk,
                                                      const float* __restrict__ pastv, const float* __restrict__ knew,
                                                      const float* __restrict__ vnew, const int* __restrict__ beam,
                                                      float* __restrict__ pctx, float* __restrict__ pm,
                                                      float* __restrict__ pl){
  __shared__ u16 Qs[4][8192];   // per consumer wave: [64 q][128 d], chunk-swizzled (pre-swizzled in qrope)
  __shared__ u16 Ks[2][4096];   // [buf][32 t][128 d], chunk swz (dc&8)|((dc^t)&7)
  __shared__ u16 Vs[2][4608];   // [buf][128 d][stride 36], t-quad slot = q ^ swz2(d) ^ (d>>5)
  int kv = blockIdx.x, b = blockIdx.y, chunk = blockIdx.z;
  int tid = threadIdx.x, lane = tid & 63, w = tid >> 6;
  int l15 = lane & 15, lh = lane >> 4;
  constexpr int NT = 64;

  if (w >= 4){
    // ================= producer =================
    int p = w - 4;
    int dblk = l15;               // 8-d block
    int tq = p * 8 + lh * 2;      // tile-local t (even); stages rows tq, tq+1
    int bmb = beam[b];
    const float* kpast = pastk + (size_t)(bmb * 8 + kv) * 4032 * 128;
    const float* vpast = pastv + (size_t)(bmb * 8 + kv) * 4032 * 128;
    const float* knb = knew + (size_t)(b * 8 + kv) * 64 * 128;
    const float* vnb = vnew + (size_t)(b * 8 + kv) * 64 * 128;

    auto loadTile = [&](int tix, float4* rk, float4* rv){
      int tg0 = chunk * 2048 + tix * 32;
      const float *ksrc, *vsrc;
      if (tg0 >= 4032){ ksrc = knb + (size_t)(tg0 - 4032) * 128; vsrc = vnb + (size_t)(tg0 - 4032) * 128; }
      else            { ksrc = kpast + (size_t)tg0 * 128;         vsrc = vpast + (size_t)tg0 * 128; }
      const float* k0 = ksrc + (size_t)tq * 128 + dblk * 8;
      const float* k1 = ksrc + (size_t)(tq + 1) * 128 + dblk * 8;
      const float* v0 = vsrc + (size_t)tq * 128 + dblk * 8;
      const float* v1 = vsrc + (size_t)(tq + 1) * 128 + dblk * 8;
      rk[0] = *(const float4*)k0; rk[1] = *(const float4*)(k0 + 4);
      rk[2] = *(const float4*)k1; rk[3] = *(const float4*)(k1 + 4);
      rv[0] = *(const float4*)v0; rv[1] = *(const float4*)(v0 + 4);
      rv[2] = *(const float4*)v1; rv[3] = *(const float4*)(v1 + 4);
    };
    auto writeTile = [&](int buf, const float4* rk, const float4* rv){
      uint4 pk0, pk1;
      pk0.x = cvtpk(rk[0].x, rk[0].y); pk0.y = cvtpk(rk[0].z, rk[0].w);
      pk0.z = cvtpk(rk[1].x, rk[1].y); pk0.w = cvtpk(rk[1].z, rk[1].w);
      pk1.x = cvtpk(rk[2].x, rk[2].y); pk1.y = cvtpk(rk[2].z, rk[2].w);
      pk1.z = cvtpk(rk[3].x, rk[3].y); pk1.w = cvtpk(rk[3].z, rk[3].w);
      int dcs0 = (dblk & 8) | ((dblk ^ tq) & 7);
      int dcs1 = (dblk & 8) | ((dblk ^ (tq + 1)) & 7);
      *(uint4*)(&Ks[buf][tq * 128 + dcs0 * 8])       = pk0;
      *(uint4*)(&Ks[buf][(tq + 1) * 128 + dcs1 * 8]) = pk1;
      float va[8] = {rv[0].x, rv[0].y, rv[0].z, rv[0].w, rv[1].x, rv[1].y, rv[1].z, rv[1].w};
      float vb[8] = {rv[2].x, rv[2].y, rv[2].z, rv[2].w, rv[3].x, rv[3].y, rv[3].z, rv[3].w};
      #pragma unroll
      for (int dd = 0; dd < 8; ++dd){
        int d = dblk * 8 + dd;
        int cc = (p ^ ((dblk ^ dd) & 3) ^ (dblk >> 2)) & 3;   // chunk=p, swz ((d>>3)^d)&3 ^ (d>>5)
        *(u32*)(&Vs[buf][d * 36 + cc * 8 + lh * 2]) = cvtpk(va[dd], vb[dd]);
      }
    };

    float4 rkA[4], rvA[4], rkB[4], rvB[4];
    loadTile(0, rkA, rvA);
    asm volatile("s_waitcnt vmcnt(0)" ::: "memory");
    writeTile(0, rkA, rvA);
    loadTile(1, rkB, rvB);
    asm volatile("s_waitcnt lgkmcnt(0)" ::: "memory");
    __builtin_amdgcn_sched_barrier(0);
    __builtin_amdgcn_s_barrier();
    __builtin_amdgcn_sched_barrier(0);
    for (int it = 0; it < NT; it += 2){
      // consumer on buf0 (tile it); stage tile it+1 -> buf1 from B; prefetch it+2 -> A
      if (it + 1 < NT){
        asm volatile("s_waitcnt vmcnt(0)" ::: "memory");
        writeTile(1, rkB, rvB);
        if (it + 2 < NT) loadTile(it + 2, rkA, rvA);
        asm volatile("s_waitcnt lgkmcnt(0)" ::: "memory");
      }
      __builtin_amdgcn_sched_barrier(0);
      __builtin_amdgcn_s_barrier();
      __builtin_amdgcn_sched_barrier(0);
      // consumer on buf1 (tile it+1); stage tile it+2 -> buf0 from A; prefetch it+3 -> B
      if (it + 2 < NT){
        asm volatile("s_waitcnt vmcnt(0)" ::: "memory");
        writeTile(0, rkA, rvA);
        if (it + 3 < NT) loadTile(it + 3, rkB, rvB);
        asm volatile("s_waitcnt lgkmcnt(0)" ::: "memory");
      }
      __builtin_amdgcn_sched_barrier(0);
      __builtin_amdgcn_s_barrier();
      __builtin_amdgcn_sched_barrier(0);
    }
    return;
  }

  // ================= consumer =================
  // stage own Q (pre-swizzled in qrope -> linear copy keeps swizzle)
  const u16* qb = qrope + (size_t)((b * 32 + kv * 4 + w) * 64) * 128;
  #pragma unroll
  for (int c = 0; c < 16; ++c)
    llds16((const char*)qb + c * 1024 + lane * 16, (char*)(&Qs[w][0]) + c * 1024);
  asm volatile("s_waitcnt vmcnt(0)" ::: "memory");

  f32x4 cacc[8][4];             // [nd][qm]: ctx^T rows d=nd*16+lh*4+r, cols q=qm*16+l15
  float mrow[4], lrow[4];
  #pragma unroll
  for (int qm = 0; qm < 4; ++qm){ mrow[qm] = -3.0e38f; lrow[qm] = 0.f; }
  #pragma unroll
  for (int nd = 0; nd < 8; ++nd)
    #pragma unroll
    for (int qm = 0; qm < 4; ++qm) cacc[nd][qm] = f32x4{0.f, 0.f, 0.f, 0.f};

  __builtin_amdgcn_sched_barrier(0);
  __builtin_amdgcn_s_barrier();
  __builtin_amdgcn_sched_barrier(0);

  for (int it = 0; it < NT; ++it){
    const u16* Kc = &Ks[it & 1][0];
    const u16* Vc = &Vs[it & 1][0];

    // S^T = K * Q^T : sacc[tt][qm] rows t=tt*16+lh*4+r, cols q=qm*16+l15
    f32x4 sacc[2][4];
    #pragma unroll
    for (int tt = 0; tt < 2; ++tt)
      #pragma unroll
      for (int qm = 0; qm < 4; ++qm) sacc[tt][qm] = f32x4{0.f, 0.f, 0.f, 0.f};
    __builtin_amdgcn_s_setprio(1);
    #pragma unroll
    for (int ks = 0; ks < 4; ++ks){
      int dc = ks * 4 + lh;
      int dcs = (dc & 8) | ((dc ^ l15) & 7);
      uint4 kf0 = *(const uint4*)(Kc + l15 * 128 + dcs * 8);
      uint4 kf1 = *(const uint4*)(Kc + (16 + l15) * 128 + dcs * 8);
      #pragma unroll
      for (int qm = 0; qm < 4; ++qm){
        uint4 qf = *(const uint4*)(&Qs[w][(qm * 16 + l15) * 128 + dcs * 8]);
        sacc[0][qm] = __builtin_amdgcn_mfma_f32_16x16x32_bf16(as_bf(kf0), as_bf(qf), sacc[0][qm], 0, 0, 0);
        sacc[1][qm] = __builtin_amdgcn_mfma_f32_16x16x32_bf16(as_bf(kf1), as_bf(qf), sacc[1][qm], 0, 0, 0);
      }
    }
    __builtin_amdgcn_s_setprio(0);

    // causal mask: only last two tiles of chunk 1 (new tokens start at t=4032)
    if (chunk == 1 && it >= 62){
      int toff = (it - 62) * 32;
      #pragma unroll
      for (int tt = 0; tt < 2; ++tt)
        #pragma unroll
        for (int qm = 0; qm < 4; ++qm)
          #pragma unroll
          for (int r = 0; r < 4; ++r){
            int t = toff + tt * 16 + lh * 4 + r;
            int q = qm * 16 + l15;
            if (t > q) sacc[tt][qm][r] = -3.0e38f;
          }
    }

    // lazy online softmax: lane-local max check; full reduce+rescale only on trigger;
    // l kept as lane-local partial (sum is linear) and reduced once after the loop.
    #pragma unroll
    for (int qm = 0; qm < 4; ++qm){
      float rm = sacc[0][qm][0];
      #pragma unroll
      for (int tt = 0; tt < 2; ++tt)
        #pragma unroll
        for (int r = 0; r < 4; ++r) rm = fmaxf(rm, sacc[tt][qm][r]);
      if (__any(rm > mrow[qm] + 8.0f)){          // defer-max (log2 units)
        rm = fmaxf(rm, __shfl_xor(rm, 16));
        rm = fmaxf(rm, __shfl_xor(rm, 32));
        float mn = fmaxf(mrow[qm], rm);
        float esc = exp2f(mrow[qm] - mn);
        mrow[qm] = mn;
        lrow[qm] *= esc;
        #pragma unroll
        for (int nd = 0; nd < 8; ++nd) cacc[nd][qm] *= esc;
      }
      float s = 0.f;
      #pragma unroll
      for (int tt = 0; tt < 2; ++tt)
        #pragma unroll
        for (int r = 0; r < 4; ++r){
          float pp = exp2f(sacc[tt][qm][r] - mrow[qm]);
          sacc[tt][qm][r] = pp;
          s += pp;
        }
      lrow[qm] += s;                             // lane-local partial
    }

    // ctx^T += V^T * P^T via 16x16x16 MFMA (P in registers)
    __builtin_amdgcn_s_setprio(1);
    #pragma unroll
    for (int tt = 0; tt < 2; ++tt){
      s16x4 pa[4];
      #pragma unroll
      for (int qm = 0; qm < 4; ++qm){
        uint2 u;
        u.x = cvtpk(sacc[tt][qm][0], sacc[tt][qm][1]);
        u.y = cvtpk(sacc[tt][qm][2], sacc[tt][qm][3]);
        pa[qm] = __builtin_bit_cast(s16x4, u);
      }
      #pragma unroll
      for (int nd = 0; nd < 8; ++nd){
        int swzv = ((nd * 2) ^ (l15 >> 3) ^ l15) & 3;          // ((d>>3)^d)&3
        int cc = ((tt * 2 + (lh >> 1)) ^ swzv ^ (nd >> 1)) & 3;
        uint2 vr = *(const uint2*)(Vc + (nd * 16 + l15) * 36 + cc * 8 + (lh & 1) * 4);
        s16x4 vfr = __builtin_bit_cast(s16x4, vr);
        #pragma unroll
        for (int qm = 0; qm < 4; ++qm)
          cacc[nd][qm] = mfma16(vfr, pa[qm], cacc[nd][qm]);
      }
    }
    __builtin_amdgcn_s_setprio(0);
    __builtin_amdgcn_sched_barrier(0);
    __builtin_amdgcn_s_barrier();
    __builtin_amdgcn_sched_barrier(0);
  }

  // reduce lane-local l partials across the 4 lh replicas of each q
  #pragma unroll
  for (int qm = 0; qm < 4; ++qm){
    lrow[qm] += __shfl_xor(lrow[qm], 16);
    lrow[qm] += __shfl_xor(lrow[qm], 32);
  }

  // unnormalized partials (contiguous stores) + (m,l)
  float* pc = pctx + (size_t)(((chunk * 16 + b) * 8 + kv) * 4 + w) * 8192;
  #pragma unroll
  for (int qm = 0; qm < 4; ++qm){
    int q = qm * 16 + l15;
    #pragma unroll
    for (int nd = 0; nd < 8; ++nd)
      *(f32x4*)(pc + (size_t)q * 128 + nd * 16 + lh * 4) = cacc[nd][qm];
  }
  if (lh == 0){
    size_t mb = (size_t)((chunk * 16 + b) * 8 + kv) * 256 + w * 64;
    #pragma unroll
    for (int qm = 0; qm < 4; ++qm){
      pm[mb + qm * 16 + l15] = mrow[qm];
      pl[mb + qm * 16 + l15] = lrow[qm];
    }
  }
}

// ---------------- combine the 2 chunk partials ----------------
__global__ __launch_bounds__(256) void combine_kernel(const float* __restrict__ pctx, const float* __restrict__ pm,
                                                      const float* __restrict__ pl, u16* __restrict__ ctxb){
  int z = blockIdx.x;
  int g = z & 3, kv = (z >> 2) & 7, b = z >> 5;
  int tid = threadIdx.x;
  int s = tid >> 2, dq = (tid & 3) * 32;
  float mv[2], lv[2];
  #pragma unroll
  for (int c = 0; c < 2; ++c){
    size_t mi = (size_t)((c * 16 + b) * 8 + kv) * 256 + g * 64 + s;
    mv[c] = pm[mi]; lv[c] = pl[mi];
  }
  float M = fmaxf(mv[0], mv[1]);
  float wc[2], wsum = 0.f;
  #pragma unroll
  for (int c = 0; c < 2; ++c){ wc[c] = exp2f(mv[c] - M); wsum += wc[c] * lv[c]; }
  float inv = 1.0f / wsum;
  u16* dst = ctxb + (size_t)(b * 64 + s) * 4096 + (kv * 4 + g) * 128 + dq;
  #pragma unroll
  for (int j4 = 0; j4 < 8; ++j4){
    float4 a = {0.f, 0.f, 0.f, 0.f};
    #pragma unroll
    for (int c = 0; c < 2; ++c){
      const float* p = pctx + (size_t)(((c * 16 + b) * 8 + kv) * 4 + g) * 8192 + s * 128 + dq + j4 * 4;
      float4 v = *(const float4*)p;
      a.x += wc[c] * v.x; a.y += wc[c] * v.y; a.z += wc[c] * v.z; a.w += wc[c] * v.w;
    }
    u16 t4[4] = {f2bf(a.x * inv), f2bf(a.y * inv), f2bf(a.z * inv), f2bf(a.w * inv)};
    *(uint2*)(dst + j4 * 4) = *(const uint2*)t4;
  }
}

extern "C" void kernel_launch(void* const* d_in, const int* in_sizes, int n_in,
                              void* d_out, int out_size, void* d_ws, size_t ws_size,
                              hipStream_t stream){
  const float* hidden = (const float*)d_in[0];
  const float* pastk  = (const float*)d_in[1];
  const float* pastv  = (const float*)d_in[2];
  const float* qw     = (const float*)d_in[3];
  const float* kw     = (const float*)d_in[4];
  const float* vw     = (const float*)d_in[5];
  const float* ow     = (const float*)d_in[6];
  const int*   beam   = (const int*)d_in[7];

  char* ws = (char*)d_ws;
  size_t off = 0;
  auto alloc = [&](size_t sz){ char* p = ws + off; off += sz; return p; };
  u16*   wtall = (u16*)alloc(50331648);     // [6144][4096] bf16: q,k,v weights transposed
  u16*   wto   = (u16*)alloc(33554432);     // [4096][4096] bf16: out_wei transposed
  u16*   hidb  = (u16*)alloc(8388608);      // hidden bf16 [1024][4096]
  u16*   qkvp  = (u16*)alloc(12582912);     // QKV proj [1024][6144]
  u16*   qrope = (u16*)alloc(8388608);      // [16][32][64][128] swizzled
  float* knew  = (float*)alloc(4194304);    // [16][8][64][128] fp32 roped new K
  float* vnew  = (float*)alloc(4194304);    // [16][8][64][128] fp32 new V
  float* pctx  = (float*)alloc(33554432);   // [2][16][8][4][64][128]
  float* pm    = (float*)alloc(262144);
  float* pl    = (float*)alloc(262144);
  u16*   ctxb  = (u16*)alloc(8388608);      // [1024][4096]
  float2* tbl  = (float2*)alloc(32768);     // [64 s][64 j] cos/sin
  if (off > ws_size) return;                // workspace too small -> fail loudly

  trig_kernel<<<16, 256, 0, stream>>>(tbl);
  cvt_hid_kernel<<<2048, 256, 0, stream>>>(hidden, hidb);
  wtrans_kernel<<<10240, 256, 0, stream>>>(qw, kw, vw, ow, wtall, wto);
  gemm_kernel<0><<<768, 256, 0, stream>>>(hidb, wtall, (void*)qkvp, 6144, 96);
  rope_kernel<<<640, 256, 0, stream>>>(qkvp, tbl, qrope, knew, vnew);
  attn_kernel<<<dim3(8, 16, 2), 512, 0, stream>>>(qrope, pastk, pastv, knew, vnew, beam, pctx, pm, pl);
  combine_kernel<<<512, 256, 0, stream>>>(pctx, pm, pl, ctxb);
  gemm_kernel<1><<<512, 256, 0, stream>>>(ctxb, wto, d_out, 4096, 64);
}

// Round 16
// 387.980 us; speedup vs baseline: 1.2386x; 1.0075x over previous
//
#include <hip/hip_runtime.h>
#include <stdint.h>

#define DEVFN __device__ __forceinline__

typedef unsigned short u16;
typedef unsigned int u32;

using f32x4 = __attribute__((ext_vector_type(4))) float;
using bfv8  = __attribute__((ext_vector_type(8))) short;   // 8 bf16 = 4 VGPR
using s16x4 = __attribute__((ext_vector_type(4))) short;   // 4 bf16 = 2 VGPR

#define CSC 0.12751745f   // (1/sqrt(128)) * log2(e)  -- folded into Q

DEVFN u16 f2bf(float f){
  u32 u = __float_as_uint(f);
  u32 r = u + 0x7FFFu + ((u >> 16) & 1u);
  return (u16)(r >> 16);
}
DEVFN float bf2f(u16 h){ return __uint_as_float(((u32)h) << 16); }

DEVFN void llds16(const void* g, void* l){
  __builtin_amdgcn_global_load_lds((const __attribute__((address_space(1))) void*)g,
                                   (__attribute__((address_space(3))) void*)l, 16, 0, 0);
}

DEVFN bfv8 as_bf(uint4 v){ return __builtin_bit_cast(bfv8, v); }

#if __has_builtin(__builtin_amdgcn_mfma_f32_16x16x16bf16_1k)
DEVFN f32x4 mfma16(s16x4 a, s16x4 b, f32x4 c){
  return __builtin_amdgcn_mfma_f32_16x16x16bf16_1k(a, b, c, 0, 0, 0);
}
#else
DEVFN f32x4 mfma16(s16x4 a, s16x4 b, f32x4 c){
  asm("v_mfma_f32_16x16x16_bf16 %0, %1, %2, %0" : "+v"(c) : "v"(a), "v"(b));
  return c;
}
#endif

DEVFN u32 cvtpk(float lo, float hi){
  u32 w;
  asm("v_cvt_pk_bf16_f32 %0, %1, %2" : "=v"(w) : "v"(lo), "v"(hi));
  return w;
}

// ---------------- cast hidden fp32 -> bf16 ----------------
__global__ __launch_bounds__(256) void cvt_hid_kernel(const float* __restrict__ src, u16* __restrict__ dst){
  int i = blockIdx.x * 256 + threadIdx.x;           // 8 elems per thread
  const float* s = src + (size_t)i * 8;
  float4 a = *(const float4*)s;
  float4 b = *(const float4*)(s + 4);
  u16 t[8] = {f2bf(a.x), f2bf(a.y), f2bf(a.z), f2bf(a.w),
              f2bf(b.x), f2bf(b.y), f2bf(b.z), f2bf(b.w)};
  *(uint4*)(dst + (size_t)i * 8) = *(const uint4*)t;
}

// ---------------- trig table: [64 s][64 j] (cos, sin) ----------------
__global__ __launch_bounds__(256) void trig_kernel(float2* __restrict__ tbl){
  int i = blockIdx.x * 256 + threadIdx.x;   // 4096 entries
  int s = i >> 6, j = i & 63;
  float inv = expf(-(float)j * 0.14391157f);   // 1/10000^(j/64)
  float ang = (4032.0f + (float)s) * inv;
  tbl[i] = make_float2(cosf(ang), sinf(ang));
}

// ---------------- weights: fp32 [K][N] -> bf16 B^T [N][K] (K=4096) ----------------
__global__ __launch_bounds__(256) void wtrans_kernel(const float* __restrict__ qw, const float* __restrict__ kw,
                                                     const float* __restrict__ vw, const float* __restrict__ ow,
                                                     u16* __restrict__ wtall, u16* __restrict__ wto){
  __shared__ float tile[64 * 65];
  int z = blockIdx.x, tid = threadIdx.x;
  const float* W; u16* WT; int Ndim; int rz;
  if (z < 4096)      { W = qw; WT = wtall;                         Ndim = 4096; rz = z; }
  else if (z < 5120) { W = kw; WT = wtall + (size_t)4096 * 4096;   Ndim = 1024; rz = z - 4096; }
  else if (z < 6144) { W = vw; WT = wtall + (size_t)5120 * 4096;   Ndim = 1024; rz = z - 5120; }
  else               { W = ow; WT = wto;                           Ndim = 4096; rz = z - 6144; }
  int ntn = Ndim >> 6;
  int tk = rz / ntn, tn = rz % ntn;
  const float* src = W + (size_t)(tk * 64) * Ndim + tn * 64;
  #pragma unroll
  for (int it = 0; it < 4; ++it){
    int fi = tid + it * 256;          // float4 index (1024 total)
    int r = fi >> 4, c4 = (fi & 15) * 4;
    float4 v = *(const float4*)(src + (size_t)r * Ndim + c4);
    tile[r * 65 + c4 + 0] = v.x; tile[r * 65 + c4 + 1] = v.y;
    tile[r * 65 + c4 + 2] = v.z; tile[r * 65 + c4 + 3] = v.w;
  }
  __syncthreads();
  u16* dst = WT + (size_t)(tn * 64) * 4096 + tk * 64;
  #pragma unroll
  for (int it = 0; it < 2; ++it){
    int ci = tid + it * 256;          // chunk of 8 (512 total)
    int n = ci >> 3, k8 = (ci & 7) * 8;
    u16 tmp[8];
    #pragma unroll
    for (int j = 0; j < 8; ++j) tmp[j] = f2bf(tile[(k8 + j) * 65 + n]);
    *(uint4*)(dst + (size_t)n * 4096 + k8) = *(const uint4*)tmp;
  }
}

// ---------------- bf16 GEMM, 128x64 tile + XCD swizzle: C[M,N] = A[M,4096] * (BT[N,4096])^T ----------------
template<int OUTF32>
__global__ __launch_bounds__(256) void gemm_kernel(const u16* __restrict__ A, const u16* __restrict__ BT,
                                                   void* __restrict__ Cv, int N, int ntn){
  constexpr int K = 4096;
  __shared__ u16 As[2][128 * 32];
  __shared__ u16 Bs[2][64 * 32];
  int bid = blockIdx.x;
  {  // XCD-aware swizzle (T1): grid %8 == 0 for both call sites
    int cpx = gridDim.x >> 3;
    bid = (bid & 7) * cpx + (bid >> 3);
  }
  int bm = bid / ntn, bn = bid % ntn;
  int tid = threadIdx.x, lane = tid & 63, w = tid >> 6;
  int wr = w >> 1, wc = w & 1;
  int l15 = lane & 15, lh = lane >> 4;
  const u16* Ab = A  + (size_t)(bm * 128) * K;
  const u16* Bb = BT + (size_t)(bn * 64) * K;
  f32x4 acc[4][2];
  #pragma unroll
  for (int m = 0; m < 4; ++m)
    #pragma unroll
    for (int n = 0; n < 2; ++n) acc[m][n] = f32x4{0.f, 0.f, 0.f, 0.f};

  auto stage = [&](int buf, int k0){
    #pragma unroll
    for (int p = 0; p < 2; ++p){
      int cid = tid + p * 256;
      int row = cid >> 2, k8 = (cid & 3) * 8;
      llds16(Ab + (size_t)row * K + k0 + k8, (char*)(&As[buf][0]) + p * 4096 + w * 1024);
    }
    {
      int row = tid >> 2, k8 = (tid & 3) * 8;
      llds16(Bb + (size_t)row * K + k0 + k8, (char*)(&Bs[buf][0]) + w * 1024);
    }
  };
  stage(0, 0);
  __syncthreads();
  for (int kt = 0; kt < K / 32; ++kt){
    int cur = kt & 1;
    if (kt + 1 < K / 32) stage(cur ^ 1, (kt + 1) * 32);
    uint4 af[4], bfr[2];
    #pragma unroll
    for (int i = 0; i < 4; ++i)
      af[i]  = *(const uint4*)(&As[cur][(wr * 64 + i * 16 + l15) * 32 + lh * 8]);
    #pragma unroll
    for (int i = 0; i < 2; ++i)
      bfr[i] = *(const uint4*)(&Bs[cur][(wc * 32 + i * 16 + l15) * 32 + lh * 8]);
    #pragma unroll
    for (int m = 0; m < 4; ++m)
      #pragma unroll
      for (int n = 0; n < 2; ++n)
        acc[m][n] = __builtin_amdgcn_mfma_f32_16x16x32_bf16(as_bf(af[m]), as_bf(bfr[n]), acc[m][n], 0, 0, 0);
    __syncthreads();
  }
  int row0 = bm * 128 + wr * 64, col0 = bn * 64 + wc * 32;
  if (OUTF32){
    float* C = (float*)Cv;
    #pragma unroll
    for (int m = 0; m < 4; ++m)
      #pragma unroll
      for (int n = 0; n < 2; ++n)
        #pragma unroll
        for (int r = 0; r < 4; ++r)
          C[(size_t)(row0 + m * 16 + lh * 4 + r) * N + col0 + n * 16 + l15] = acc[m][n][r];
  } else {
    u16* C = (u16*)Cv;
    #pragma unroll
    for (int m = 0; m < 4; ++m)
      #pragma unroll
      for (int n = 0; n < 2; ++n)
        #pragma unroll
        for (int r = 0; r < 4; ++r)
          C[(size_t)(row0 + m * 16 + lh * 4 + r) * N + col0 + n * 16 + l15] = f2bf(acc[m][n][r]);
  }
}

// ---------------- RoPE (table-driven): Q (scaled, SWIZZLED) -> qrope ; K -> knew fp32 ; V copy -> vnew ----------------
__global__ __launch_bounds__(256) void rope_kernel(const u16* __restrict__ qkvp, const float2* __restrict__ tbl,
                                                   u16* __restrict__ qrope, float* __restrict__ knew,
                                                   float* __restrict__ vnew){
  int z = blockIdx.x, tid = threadIdx.x;
  if (z < 512){
    int b = z >> 5, h = z & 31;
    u16* dst = qrope + (size_t)((b * 32 + h) * 64) * 128;
    for (int it = 0; it < 16; ++it){
      int i = tid + it * 256;
      int s = i >> 6, j = i & 63;
      const u16* src = qkvp + (size_t)(b * 64 + s) * 6144 + h * 128;
      float q0 = bf2f(src[j]), q1 = bf2f(src[j + 64]);
      float2 t = tbl[i];
      float cs = t.x, sn = t.y;
      // swizzled store: elem (q=s, d) at q*128 + ((dc&8)|((dc^q)&7))*8 + (d&7)
      int dcs = ((j >> 3) ^ s) & 7;
      dst[s * 128 + dcs * 8 + (j & 7)]      = f2bf((q0 * cs - q1 * sn) * CSC);
      dst[s * 128 + 64 + dcs * 8 + (j & 7)] = f2bf((q1 * cs + q0 * sn) * CSC);
    }
  } else {
    int z2 = z - 512, b = z2 >> 3, kvh = z2 & 7;
    for (int it = 0; it < 16; ++it){
      int i = tid + it * 256;
      int s = i >> 6, j = i & 63;
      const u16* src = qkvp + (size_t)(b * 64 + s) * 6144 + 4096 + kvh * 128;
      float q0 = bf2f(src[j]), q1 = bf2f(src[j + 64]);
      float2 t = tbl[i];
      float cs = t.x, sn = t.y;
      float* kd = knew + ((size_t)(b * 8 + kvh) * 64 + s) * 128;
      kd[j]      = q0 * cs - q1 * sn;
      kd[j + 64] = q1 * cs + q0 * sn;
      const u16* vs = qkvp + (size_t)(b * 64 + s) * 6144 + 5120 + kvh * 128;
      float* vd = vnew + ((size_t)(b * 8 + kvh) * 64 + s) * 128;
      vd[j]      = bf2f(vs[j]);
      vd[j + 64] = bf2f(vs[j + 64]);
    }
  }
}

// ---------------- flash attention (r9/r12 verbatim: Q in LDS, producer/consumer, double-ring) ----------------
// block: 512 thr = 4 consumer waves (one head each, Q in per-wave LDS) + 4 producer waves
// 2 T-chunks of 2048 -> grid 256 blocks = 1/CU, NT=64 tiles of 32 t
__global__ __launch_bounds__(512, 2) void attn_kernel(const u16* __restrict__ qrope, const float* __restrict__ pastk,
                                                      const float* __restrict__ pastv, const float* __restrict__ knew,
                                                      const float* __restrict__ vnew, const int* __restrict__ beam,
                                                      float* __restrict__ pctx, float* __restrict__ pm,
                                                      float* __restrict__ pl){
  __shared__ u16 Qs[4][8192];   // per consumer wave: [64 q][128 d], chunk-swizzled (pre-swizzled in qrope)
  __shared__ u16 Ks[2][4096];   // [buf][32 t][128 d], chunk swz (dc&8)|((dc^t)&7)
  __shared__ u16 Vs[2][4608];   // [buf][128 d][stride 36], t-quad slot = q ^ swz2(d) ^ (d>>5)
  int kv = blockIdx.x, b = blockIdx.y, chunk = blockIdx.z;
  int tid = threadIdx.x, lane = tid & 63, w = tid >> 6;
  int l15 = lane & 15, lh = lane >> 4;
  constexpr int NT = 64;

  if (w >= 4){
    // ================= producer =================
    int p = w - 4;
    int dblk = l15;               // 8-d block
    int tq = p * 8 + lh * 2;      // tile-local t (even); stages rows tq, tq+1
    int bmb = beam[b];
    const float* kpast = pastk + (size_t)(bmb * 8 + kv) * 4032 * 128;
    const float* vpast = pastv + (size_t)(bmb * 8 + kv) * 4032 * 128;
    const float* knb = knew + (size_t)(b * 8 + kv) * 64 * 128;
    const float* vnb = vnew + (size_t)(b * 8 + kv) * 64 * 128;

    auto loadTile = [&](int tix, float4* rk, float4* rv){
      int tg0 = chunk * 2048 + tix * 32;
      const float *ksrc, *vsrc;
      if (tg0 >= 4032){ ksrc = knb + (size_t)(tg0 - 4032) * 128; vsrc = vnb + (size_t)(tg0 - 4032) * 128; }
      else            { ksrc = kpast + (size_t)tg0 * 128;         vsrc = vpast + (size_t)tg0 * 128; }
      const float* k0 = ksrc + (size_t)tq * 128 + dblk * 8;
      const float* k1 = ksrc + (size_t)(tq + 1) * 128 + dblk * 8;
      const float* v0 = vsrc + (size_t)tq * 128 + dblk * 8;
      const float* v1 = vsrc + (size_t)(tq + 1) * 128 + dblk * 8;
      rk[0] = *(const float4*)k0; rk[1] = *(const float4*)(k0 + 4);
      rk[2] = *(const float4*)k1; rk[3] = *(const float4*)(k1 + 4);
      rv[0] = *(const float4*)v0; rv[1] = *(const float4*)(v0 + 4);
      rv[2] = *(const float4*)v1; rv[3] = *(const float4*)(v1 + 4);
    };
    auto writeTile = [&](int buf, const float4* rk, const float4* rv){
      uint4 pk0, pk1;
      pk0.x = cvtpk(rk[0].x, rk[0].y); pk0.y = cvtpk(rk[0].z, rk[0].w);
      pk0.z = cvtpk(rk[1].x, rk[1].y); pk0.w = cvtpk(rk[1].z, rk[1].w);
      pk1.x = cvtpk(rk[2].x, rk[2].y); pk1.y = cvtpk(rk[2].z, rk[2].w);
      pk1.z = cvtpk(rk[3].x, rk[3].y); pk1.w = cvtpk(rk[3].z, rk[3].w);
      int dcs0 = (dblk & 8) | ((dblk ^ tq) & 7);
      int dcs1 = (dblk & 8) | ((dblk ^ (tq + 1)) & 7);
      *(uint4*)(&Ks[buf][tq * 128 + dcs0 * 8])       = pk0;
      *(uint4*)(&Ks[buf][(tq + 1) * 128 + dcs1 * 8]) = pk1;
      float va[8] = {rv[0].x, rv[0].y, rv[0].z, rv[0].w, rv[1].x, rv[1].y, rv[1].z, rv[1].w};
      float vb[8] = {rv[2].x, rv[2].y, rv[2].z, rv[2].w, rv[3].x, rv[3].y, rv[3].z, rv[3].w};
      #pragma unroll
      for (int dd = 0; dd < 8; ++dd){
        int d = dblk * 8 + dd;
        int cc = (p ^ ((dblk ^ dd) & 3) ^ (dblk >> 2)) & 3;   // chunk=p, swz ((d>>3)^d)&3 ^ (d>>5)
        *(u32*)(&Vs[buf][d * 36 + cc * 8 + lh * 2]) = cvtpk(va[dd], vb[dd]);
      }
    };

    float4 rkA[4], rvA[4], rkB[4], rvB[4];
    loadTile(0, rkA, rvA);
    asm volatile("s_waitcnt vmcnt(0)" ::: "memory");
    writeTile(0, rkA, rvA);
    loadTile(1, rkB, rvB);
    asm volatile("s_waitcnt lgkmcnt(0)" ::: "memory");
    __builtin_amdgcn_sched_barrier(0);
    __builtin_amdgcn_s_barrier();
    __builtin_amdgcn_sched_barrier(0);
    for (int it = 0; it < NT; it += 2){
      // consumer on buf0 (tile it); stage tile it+1 -> buf1 from B; prefetch it+2 -> A
      if (it + 1 < NT){
        asm volatile("s_waitcnt vmcnt(0)" ::: "memory");
        writeTile(1, rkB, rvB);
        if (it + 2 < NT) loadTile(it + 2, rkA, rvA);
        asm volatile("s_waitcnt lgkmcnt(0)" ::: "memory");
      }
      __builtin_amdgcn_sched_barrier(0);
      __builtin_amdgcn_s_barrier();
      __builtin_amdgcn_sched_barrier(0);
      // consumer on buf1 (tile it+1); stage tile it+2 -> buf0 from A; prefetch it+3 -> B
      if (it + 2 < NT){
        asm volatile("s_waitcnt vmcnt(0)" ::: "memory");
        writeTile(0, rkA, rvA);
        if (it + 3 < NT) loadTile(it + 3, rkB, rvB);
        asm volatile("s_waitcnt lgkmcnt(0)" ::: "memory");
      }
      __builtin_amdgcn_sched_barrier(0);
      __builtin_amdgcn_s_barrier();
      __builtin_amdgcn_sched_barrier(0);
    }
    return;
  }

  // ================= consumer =================
  // stage own Q (pre-swizzled in qrope -> linear copy keeps swizzle)
  const u16* qb = qrope + (size_t)((b * 32 + kv * 4 + w) * 64) * 128;
  #pragma unroll
  for (int c = 0; c < 16; ++c)
    llds16((const char*)qb + c * 1024 + lane * 16, (char*)(&Qs[w][0]) + c * 1024);
  asm volatile("s_waitcnt vmcnt(0)" ::: "memory");

  f32x4 cacc[8][4];             // [nd][qm]: ctx^T rows d=nd*16+lh*4+r, cols q=qm*16+l15
  float mrow[4], lrow[4];
  #pragma unroll
  for (int qm = 0; qm < 4; ++qm){ mrow[qm] = -3.0e38f; lrow[qm] = 0.f; }
  #pragma unroll
  for (int nd = 0; nd < 8; ++nd)
    #pragma unroll
    for (int qm = 0; qm < 4; ++qm) cacc[nd][qm] = f32x4{0.f, 0.f, 0.f, 0.f};

  __builtin_amdgcn_sched_barrier(0);
  __builtin_amdgcn_s_barrier();
  __builtin_amdgcn_sched_barrier(0);

  for (int it = 0; it < NT; ++it){
    const u16* Kc = &Ks[it & 1][0];
    const u16* Vc = &Vs[it & 1][0];

    // S^T = K * Q^T : sacc[tt][qm] rows t=tt*16+lh*4+r, cols q=qm*16+l15
    f32x4 sacc[2][4];
    #pragma unroll
    for (int tt = 0; tt < 2; ++tt)
      #pragma unroll
      for (int qm = 0; qm < 4; ++qm) sacc[tt][qm] = f32x4{0.f, 0.f, 0.f, 0.f};
    #pragma unroll
    for (int ks = 0; ks < 4; ++ks){
      int dc = ks * 4 + lh;
      int dcs = (dc & 8) | ((dc ^ l15) & 7);
      uint4 kf0 = *(const uint4*)(Kc + l15 * 128 + dcs * 8);
      uint4 kf1 = *(const uint4*)(Kc + (16 + l15) * 128 + dcs * 8);
      #pragma unroll
      for (int qm = 0; qm < 4; ++qm){
        uint4 qf = *(const uint4*)(&Qs[w][(qm * 16 + l15) * 128 + dcs * 8]);
        sacc[0][qm] = __builtin_amdgcn_mfma_f32_16x16x32_bf16(as_bf(kf0), as_bf(qf), sacc[0][qm], 0, 0, 0);
        sacc[1][qm] = __builtin_amdgcn_mfma_f32_16x16x32_bf16(as_bf(kf1), as_bf(qf), sacc[1][qm], 0, 0, 0);
      }
    }

    // causal mask: only last two tiles of chunk 1 (new tokens start at t=4032)
    if (chunk == 1 && it >= 62){
      int toff = (it - 62) * 32;
      #pragma unroll
      for (int tt = 0; tt < 2; ++tt)
        #pragma unroll
        for (int qm = 0; qm < 4; ++qm)
          #pragma unroll
          for (int r = 0; r < 4; ++r){
            int t = toff + tt * 16 + lh * 4 + r;
            int q = qm * 16 + l15;
            if (t > q) sacc[tt][qm][r] = -3.0e38f;
          }
    }

    // lazy online softmax: lane-local max check; full reduce+rescale only on trigger;
    // l kept as lane-local partial (sum is linear) and reduced once after the loop.
    #pragma unroll
    for (int qm = 0; qm < 4; ++qm){
      float rm = sacc[0][qm][0];
      #pragma unroll
      for (int tt = 0; tt < 2; ++tt)
        #pragma unroll
        for (int r = 0; r < 4; ++r) rm = fmaxf(rm, sacc[tt][qm][r]);
      if (__any(rm > mrow[qm] + 8.0f)){          // defer-max (log2 units)
        rm = fmaxf(rm, __shfl_xor(rm, 16));
        rm = fmaxf(rm, __shfl_xor(rm, 32));
        float mn = fmaxf(mrow[qm], rm);
        float esc = exp2f(mrow[qm] - mn);
        mrow[qm] = mn;
        lrow[qm] *= esc;
        #pragma unroll
        for (int nd = 0; nd < 8; ++nd) cacc[nd][qm] *= esc;
      }
      float s = 0.f;
      #pragma unroll
      for (int tt = 0; tt < 2; ++tt)
        #pragma unroll
        for (int r = 0; r < 4; ++r){
          float pp = exp2f(sacc[tt][qm][r] - mrow[qm]);
          sacc[tt][qm][r] = pp;
          s += pp;
        }
      lrow[qm] += s;                             // lane-local partial
    }

    // ctx^T += V^T * P^T via 16x16x16 MFMA (P in registers)
    #pragma unroll
    for (int tt = 0; tt < 2; ++tt){
      s16x4 pa[4];
      #pragma unroll
      for (int qm = 0; qm < 4; ++qm){
        uint2 u;
        u.x = cvtpk(sacc[tt][qm][0], sacc[tt][qm][1]);
        u.y = cvtpk(sacc[tt][qm][2], sacc[tt][qm][3]);
        pa[qm] = __builtin_bit_cast(s16x4, u);
      }
      #pragma unroll
      for (int nd = 0; nd < 8; ++nd){
        int swzv = ((nd * 2) ^ (l15 >> 3) ^ l15) & 3;          // ((d>>3)^d)&3
        int cc = ((tt * 2 + (lh >> 1)) ^ swzv ^ (nd >> 1)) & 3;
        uint2 vr = *(const uint2*)(Vc + (nd * 16 + l15) * 36 + cc * 8 + (lh & 1) * 4);
        s16x4 vfr = __builtin_bit_cast(s16x4, vr);
        #pragma unroll
        for (int qm = 0; qm < 4; ++qm)
          cacc[nd][qm] = mfma16(vfr, pa[qm], cacc[nd][qm]);
      }
    }
    __builtin_amdgcn_sched_barrier(0);
    __builtin_amdgcn_s_barrier();
    __builtin_amdgcn_sched_barrier(0);
  }

  // reduce lane-local l partials across the 4 lh replicas of each q
  #pragma unroll
  for (int qm = 0; qm < 4; ++qm){
    lrow[qm] += __shfl_xor(lrow[qm], 16);
    lrow[qm] += __shfl_xor(lrow[qm], 32);
  }

  // unnormalized partials (contiguous stores) + (m,l)
  float* pc = pctx + (size_t)(((chunk * 16 + b) * 8 + kv) * 4 + w) * 8192;
  #pragma unroll
  for (int qm = 0; qm < 4; ++qm){
    int q = qm * 16 + l15;
    #pragma unroll
    for (int nd = 0; nd < 8; ++nd)
      *(f32x4*)(pc + (size_t)q * 128 + nd * 16 + lh * 4) = cacc[nd][qm];
  }
  if (lh == 0){
    size_t mb = (size_t)((chunk * 16 + b) * 8 + kv) * 256 + w * 64;
    #pragma unroll
    for (int qm = 0; qm < 4; ++qm){
      pm[mb + qm * 16 + l15] = mrow[qm];
      pl[mb + qm * 16 + l15] = lrow[qm];
    }
  }
}

// ---------------- combine the 2 chunk partials ----------------
__global__ __launch_bounds__(256) void combine_kernel(const float* __restrict__ pctx, const float* __restrict__ pm,
                                                      const float* __restrict__ pl, u16* __restrict__ ctxb){
  int z = blockIdx.x;
  int g = z & 3, kv = (z >> 2) & 7, b = z >> 5;
  int tid = threadIdx.x;
  int s = tid >> 2, dq = (tid & 3) * 32;
  float mv[2], lv[2];
  #pragma unroll
  for (int c = 0; c < 2; ++c){
    size_t mi = (size_t)((c * 16 + b) * 8 + kv) * 256 + g * 64 + s;
    mv[c] = pm[mi]; lv[c] = pl[mi];
  }
  float M = fmaxf(mv[0], mv[1]);
  float wc[2], wsum = 0.f;
  #pragma unroll
  for (int c = 0; c < 2; ++c){ wc[c] = exp2f(mv[c] - M); wsum += wc[c] * lv[c]; }
  float inv = 1.0f / wsum;
  u16* dst = ctxb + (size_t)(b * 64 + s) * 4096 + (kv * 4 + g) * 128 + dq;
  #pragma unroll
  for (int j4 = 0; j4 < 8; ++j4){
    float4 a = {0.f, 0.f, 0.f, 0.f};
    #pragma unroll
    for (int c = 0; c < 2; ++c){
      const float* p = pctx + (size_t)(((c * 16 + b) * 8 + kv) * 4 + g) * 8192 + s * 128 + dq + j4 * 4;
      float4 v = *(const float4*)p;
      a.x += wc[c] * v.x; a.y += wc[c] * v.y; a.z += wc[c] * v.z; a.w += wc[c] * v.w;
    }
    u16 t4[4] = {f2bf(a.x * inv), f2bf(a.y * inv), f2bf(a.z * inv), f2bf(a.w * inv)};
    *(uint2*)(dst + j4 * 4) = *(const uint2*)t4;
  }
}

extern "C" void kernel_launch(void* const* d_in, const int* in_sizes, int n_in,
                              void* d_out, int out_size, void* d_ws, size_t ws_size,
                              hipStream_t stream){
  const float* hidden = (const float*)d_in[0];
  const float* pastk  = (const float*)d_in[1];
  const float* pastv  = (const float*)d_in[2];
  const float* qw     = (const float*)d_in[3];
  const float* kw     = (const float*)d_in[4];
  const float* vw     = (const float*)d_in[5];
  const float* ow     = (const float*)d_in[6];
  const int*   beam   = (const int*)d_in[7];

  char* ws = (char*)d_ws;
  size_t off = 0;
  auto alloc = [&](size_t sz){ char* p = ws + off; off += sz; return p; };
  u16*   wtall = (u16*)alloc(50331648);     // [6144][4096] bf16: q,k,v weights transposed
  u16*   wto   = (u16*)alloc(33554432);     // [4096][4096] bf16: out_wei transposed
  u16*   hidb  = (u16*)alloc(8388608);      // hidden bf16 [1024][4096]
  u16*   qkvp  = (u16*)alloc(12582912);     // QKV proj [1024][6144]
  u16*   qrope = (u16*)alloc(8388608);      // [16][32][64][128] swizzled
  float* knew  = (float*)alloc(4194304);    // [16][8][64][128] fp32 roped new K
  float* vnew  = (float*)alloc(4194304);    // [16][8][64][128] fp32 new V
  float* pctx  = (float*)alloc(33554432);   // [2][16][8][4][64][128]
  float* pm    = (float*)alloc(262144);
  float* pl    = (float*)alloc(262144);
  u16*   ctxb  = (u16*)alloc(8388608);      // [1024][4096]
  float2* tbl  = (float2*)alloc(32768);     // [64 s][64 j] cos/sin
  if (off > ws_size) return;                // workspace too small -> fail loudly

  trig_kernel<<<16, 256, 0, stream>>>(tbl);
  cvt_hid_kernel<<<2048, 256, 0, stream>>>(hidden, hidb);
  wtrans_kernel<<<10240, 256, 0, stream>>>(qw, kw, vw, ow, wtall, wto);
  gemm_kernel<0><<<768, 256, 0, stream>>>(hidb, wtall, (void*)qkvp, 6144, 96);
  rope_kernel<<<640, 256, 0, stream>>>(qkvp, tbl, qrope, knew, vnew);
  attn_kernel<<<dim3(8, 16, 2), 512, 0, stream>>>(qrope, pastk, pastv, knew, vnew, beam, pctx, pm, pl);
  combine_kernel<<<512, 256, 0, stream>>>(pctx, pm, pl, ctxb);
  gemm_kernel<1><<<512, 256, 0, stream>>>(ctxb, wto, d_out, 4096, 64);
}

// Round 17
// 377.498 us; speedup vs baseline: 1.2730x; 1.0278x over previous
//
#include <hip/hip_runtime.h>
#include <stdint.h>

#define DEVFN __device__ __forceinline__

typedef unsigned short u16;
typedef unsigned int u32;

using f32x4 = __attribute__((ext_vector_type(4))) float;
using bfv8  = __attribute__((ext_vector_type(8))) short;   // 8 bf16 = 4 VGPR
using s16x4 = __attribute__((ext_vector_type(4))) short;   // 4 bf16 = 2 VGPR

#define CSC 0.12751745f   // (1/sqrt(128)) * log2(e)  -- folded into Q

DEVFN u16 f2bf(float f){
  u32 u = __float_as_uint(f);
  u32 r = u + 0x7FFFu + ((u >> 16) & 1u);
  return (u16)(r >> 16);
}
DEVFN float bf2f(u16 h){ return __uint_as_float(((u32)h) << 16); }

DEVFN void llds16(const void* g, void* l){
  __builtin_amdgcn_global_load_lds((const __attribute__((address_space(1))) void*)g,
                                   (__attribute__((address_space(3))) void*)l, 16, 0, 0);
}

DEVFN bfv8 as_bf(uint4 v){ return __builtin_bit_cast(bfv8, v); }

#if __has_builtin(__builtin_amdgcn_mfma_f32_16x16x16bf16_1k)
DEVFN f32x4 mfma16(s16x4 a, s16x4 b, f32x4 c){
  return __builtin_amdgcn_mfma_f32_16x16x16bf16_1k(a, b, c, 0, 0, 0);
}
#else
DEVFN f32x4 mfma16(s16x4 a, s16x4 b, f32x4 c){
  asm("v_mfma_f32_16x16x16_bf16 %0, %1, %2, %0" : "+v"(c) : "v"(a), "v"(b));
  return c;
}
#endif

DEVFN u32 cvtpk(float lo, float hi){
  u32 w;
  asm("v_cvt_pk_bf16_f32 %0, %1, %2" : "=v"(w) : "v"(lo), "v"(hi));
  return w;
}

// ---------------- cast hidden fp32 -> bf16 (+ trig table in tail blocks) ----------------
__global__ __launch_bounds__(256) void cvt_hid_kernel(const float* __restrict__ src, u16* __restrict__ dst,
                                                      float2* __restrict__ tbl){
  int bx = blockIdx.x;
  if (bx >= 2048){                                  // trig table: [64 s][64 j] (cos, sin)
    int i = (bx - 2048) * 256 + threadIdx.x;        // 4096 entries
    int s = i >> 6, j = i & 63;
    float inv = expf(-(float)j * 0.14391157f);      // 1/10000^(j/64)
    float ang = (4032.0f + (float)s) * inv;
    tbl[i] = make_float2(cosf(ang), sinf(ang));
    return;
  }
  int i = bx * 256 + threadIdx.x;                   // 8 elems per thread
  const float* s = src + (size_t)i * 8;
  float4 a = *(const float4*)s;
  float4 b = *(const float4*)(s + 4);
  u16 t[8] = {f2bf(a.x), f2bf(a.y), f2bf(a.z), f2bf(a.w),
              f2bf(b.x), f2bf(b.y), f2bf(b.z), f2bf(b.w)};
  *(uint4*)(dst + (size_t)i * 8) = *(const uint4*)t;
}

// ---------------- weights: fp32 [K][N] -> bf16 B^T [N][K] (K=4096) ----------------
__global__ __launch_bounds__(256) void wtrans_kernel(const float* __restrict__ qw, const float* __restrict__ kw,
                                                     const float* __restrict__ vw, const float* __restrict__ ow,
                                                     u16* __restrict__ wtall, u16* __restrict__ wto){
  __shared__ float tile[64 * 65];
  int z = blockIdx.x, tid = threadIdx.x;
  const float* W; u16* WT; int Ndim; int rz;
  if (z < 4096)      { W = qw; WT = wtall;                         Ndim = 4096; rz = z; }
  else if (z < 5120) { W = kw; WT = wtall + (size_t)4096 * 4096;   Ndim = 1024; rz = z - 4096; }
  else if (z < 6144) { W = vw; WT = wtall + (size_t)5120 * 4096;   Ndim = 1024; rz = z - 5120; }
  else               { W = ow; WT = wto;                           Ndim = 4096; rz = z - 6144; }
  int ntn = Ndim >> 6;
  int tk = rz / ntn, tn = rz % ntn;
  const float* src = W + (size_t)(tk * 64) * Ndim + tn * 64;
  #pragma unroll
  for (int it = 0; it < 4; ++it){
    int fi = tid + it * 256;          // float4 index (1024 total)
    int r = fi >> 4, c4 = (fi & 15) * 4;
    float4 v = *(const float4*)(src + (size_t)r * Ndim + c4);
    tile[r * 65 + c4 + 0] = v.x; tile[r * 65 + c4 + 1] = v.y;
    tile[r * 65 + c4 + 2] = v.z; tile[r * 65 + c4 + 3] = v.w;
  }
  __syncthreads();
  u16* dst = WT + (size_t)(tn * 64) * 4096 + tk * 64;
  #pragma unroll
  for (int it = 0; it < 2; ++it){
    int ci = tid + it * 256;          // chunk of 8 (512 total)
    int n = ci >> 3, k8 = (ci & 7) * 8;
    u16 tmp[8];
    #pragma unroll
    for (int j = 0; j < 8; ++j) tmp[j] = f2bf(tile[(k8 + j) * 65 + n]);
    *(uint4*)(dst + (size_t)n * 4096 + k8) = *(const uint4*)tmp;
  }
}

// ---------------- bf16 GEMM, 128x64 tile + XCD swizzle: C[M,N] = A[M,4096] * (BT[N,4096])^T ----------------
template<int OUTF32>
__global__ __launch_bounds__(256) void gemm_kernel(const u16* __restrict__ A, const u16* __restrict__ BT,
                                                   void* __restrict__ Cv, int N, int ntn){
  constexpr int K = 4096;
  __shared__ u16 As[2][128 * 32];
  __shared__ u16 Bs[2][64 * 32];
  int bid = blockIdx.x;
  {  // XCD-aware swizzle (T1): grid %8 == 0 for both call sites
    int cpx = gridDim.x >> 3;
    bid = (bid & 7) * cpx + (bid >> 3);
  }
  int bm = bid / ntn, bn = bid % ntn;
  int tid = threadIdx.x, lane = tid & 63, w = tid >> 6;
  int wr = w >> 1, wc = w & 1;
  int l15 = lane & 15, lh = lane >> 4;
  const u16* Ab = A  + (size_t)(bm * 128) * K;
  const u16* Bb = BT + (size_t)(bn * 64) * K;
  f32x4 acc[4][2];
  #pragma unroll
  for (int m = 0; m < 4; ++m)
    #pragma unroll
    for (int n = 0; n < 2; ++n) acc[m][n] = f32x4{0.f, 0.f, 0.f, 0.f};

  auto stage = [&](int buf, int k0){
    #pragma unroll
    for (int p = 0; p < 2; ++p){
      int cid = tid + p * 256;
      int row = cid >> 2, k8 = (cid & 3) * 8;
      llds16(Ab + (size_t)row * K + k0 + k8, (char*)(&As[buf][0]) + p * 4096 + w * 1024);
    }
    {
      int row = tid >> 2, k8 = (tid & 3) * 8;
      llds16(Bb + (size_t)row * K + k0 + k8, (char*)(&Bs[buf][0]) + w * 1024);
    }
  };
  stage(0, 0);
  __syncthreads();
  for (int kt = 0; kt < K / 32; ++kt){
    int cur = kt & 1;
    if (kt + 1 < K / 32) stage(cur ^ 1, (kt + 1) * 32);
    uint4 af[4], bfr[2];
    #pragma unroll
    for (int i = 0; i < 4; ++i)
      af[i]  = *(const uint4*)(&As[cur][(wr * 64 + i * 16 + l15) * 32 + lh * 8]);
    #pragma unroll
    for (int i = 0; i < 2; ++i)
      bfr[i] = *(const uint4*)(&Bs[cur][(wc * 32 + i * 16 + l15) * 32 + lh * 8]);
    #pragma unroll
    for (int m = 0; m < 4; ++m)
      #pragma unroll
      for (int n = 0; n < 2; ++n)
        acc[m][n] = __builtin_amdgcn_mfma_f32_16x16x32_bf16(as_bf(af[m]), as_bf(bfr[n]), acc[m][n], 0, 0, 0);
    __syncthreads();
  }
  int row0 = bm * 128 + wr * 64, col0 = bn * 64 + wc * 32;
  if (OUTF32){
    float* C = (float*)Cv;
    #pragma unroll
    for (int m = 0; m < 4; ++m)
      #pragma unroll
      for (int n = 0; n < 2; ++n)
        #pragma unroll
        for (int r = 0; r < 4; ++r)
          C[(size_t)(row0 + m * 16 + lh * 4 + r) * N + col0 + n * 16 + l15] = acc[m][n][r];
  } else {
    u16* C = (u16*)Cv;
    #pragma unroll
    for (int m = 0; m < 4; ++m)
      #pragma unroll
      for (int n = 0; n < 2; ++n)
        #pragma unroll
        for (int r = 0; r < 4; ++r)
          C[(size_t)(row0 + m * 16 + lh * 4 + r) * N + col0 + n * 16 + l15] = f2bf(acc[m][n][r]);
  }
}

// ---------------- RoPE (table-driven): Q (scaled, SWIZZLED) -> qrope ; K -> knew fp32 ; V copy -> vnew ----------------
__global__ __launch_bounds__(256) void rope_kernel(const u16* __restrict__ qkvp, const float2* __restrict__ tbl,
                                                   u16* __restrict__ qrope, float* __restrict__ knew,
                                                   float* __restrict__ vnew){
  int z = blockIdx.x, tid = threadIdx.x;
  if (z < 512){
    int b = z >> 5, h = z & 31;
    u16* dst = qrope + (size_t)((b * 32 + h) * 64) * 128;
    for (int it = 0; it < 16; ++it){
      int i = tid + it * 256;
      int s = i >> 6, j = i & 63;
      const u16* src = qkvp + (size_t)(b * 64 + s) * 6144 + h * 128;
      float q0 = bf2f(src[j]), q1 = bf2f(src[j + 64]);
      float2 t = tbl[i];
      float cs = t.x, sn = t.y;
      // swizzled store: elem (q=s, d) at q*128 + ((dc&8)|((dc^q)&7))*8 + (d&7)
      int dcs = ((j >> 3) ^ s) & 7;
      dst[s * 128 + dcs * 8 + (j & 7)]      = f2bf((q0 * cs - q1 * sn) * CSC);
      dst[s * 128 + 64 + dcs * 8 + (j & 7)] = f2bf((q1 * cs + q0 * sn) * CSC);
    }
  } else {
    int z2 = z - 512, b = z2 >> 3, kvh = z2 & 7;
    for (int it = 0; it < 16; ++it){
      int i = tid + it * 256;
      int s = i >> 6, j = i & 63;
      const u16* src = qkvp + (size_t)(b * 64 + s) * 6144 + 4096 + kvh * 128;
      float q0 = bf2f(src[j]), q1 = bf2f(src[j + 64]);
      float2 t = tbl[i];
      float cs = t.x, sn = t.y;
      float* kd = knew + ((size_t)(b * 8 + kvh) * 64 + s) * 128;
      kd[j]      = q0 * cs - q1 * sn;
      kd[j + 64] = q1 * cs + q0 * sn;
      const u16* vs = qkvp + (size_t)(b * 64 + s) * 6144 + 5120 + kvh * 128;
      float* vd = vnew + ((size_t)(b * 8 + kvh) * 64 + s) * 128;
      vd[j]      = bf2f(vs[j]);
      vd[j + 64] = bf2f(vs[j + 64]);
    }
  }
}

// ---------------- flash attention (r9/r12 verbatim; bf16 partials) ----------------
// block: 512 thr = 4 consumer waves (one head each, Q in per-wave LDS) + 4 producer waves
// 2 T-chunks of 2048 -> grid 256 blocks = 1/CU, NT=64 tiles of 32 t
__global__ __launch_bounds__(512, 2) void attn_kernel(const u16* __restrict__ qrope, const float* __restrict__ pastk,
                                                      const float* __restrict__ pastv, const float* __restrict__ knew,
                                                      const float* __restrict__ vnew, const int* __restrict__ beam,
                                                      u16* __restrict__ pctx, float* __restrict__ pm,
                                                      float* __restrict__ pl){
  __shared__ u16 Qs[4][8192];   // per consumer wave: [64 q][128 d], chunk-swizzled (pre-swizzled in qrope)
  __shared__ u16 Ks[2][4096];   // [buf][32 t][128 d], chunk swz (dc&8)|((dc^t)&7)
  __shared__ u16 Vs[2][4608];   // [buf][128 d][stride 36], t-quad slot = q ^ swz2(d) ^ (d>>5)
  int kv = blockIdx.x, b = blockIdx.y, chunk = blockIdx.z;
  int tid = threadIdx.x, lane = tid & 63, w = tid >> 6;
  int l15 = lane & 15, lh = lane >> 4;
  constexpr int NT = 64;

  if (w >= 4){
    // ================= producer =================
    int p = w - 4;
    int dblk = l15;               // 8-d block
    int tq = p * 8 + lh * 2;      // tile-local t (even); stages rows tq, tq+1
    int bmb = beam[b];
    const float* kpast = pastk + (size_t)(bmb * 8 + kv) * 4032 * 128;
    const float* vpast = pastv + (size_t)(bmb * 8 + kv) * 4032 * 128;
    const float* knb = knew + (size_t)(b * 8 + kv) * 64 * 128;
    const float* vnb = vnew + (size_t)(b * 8 + kv) * 64 * 128;

    auto loadTile = [&](int tix, float4* rk, float4* rv){
      int tg0 = chunk * 2048 + tix * 32;
      const float *ksrc, *vsrc;
      if (tg0 >= 4032){ ksrc = knb + (size_t)(tg0 - 4032) * 128; vsrc = vnb + (size_t)(tg0 - 4032) * 128; }
      else            { ksrc = kpast + (size_t)tg0 * 128;         vsrc = vpast + (size_t)tg0 * 128; }
      const float* k0 = ksrc + (size_t)tq * 128 + dblk * 8;
      const float* k1 = ksrc + (size_t)(tq + 1) * 128 + dblk * 8;
      const float* v0 = vsrc + (size_t)tq * 128 + dblk * 8;
      const float* v1 = vsrc + (size_t)(tq + 1) * 128 + dblk * 8;
      rk[0] = *(const float4*)k0; rk[1] = *(const float4*)(k0 + 4);
      rk[2] = *(const float4*)k1; rk[3] = *(const float4*)(k1 + 4);
      rv[0] = *(const float4*)v0; rv[1] = *(const float4*)(v0 + 4);
      rv[2] = *(const float4*)v1; rv[3] = *(const float4*)(v1 + 4);
    };
    auto writeTile = [&](int buf, const float4* rk, const float4* rv){
      uint4 pk0, pk1;
      pk0.x = cvtpk(rk[0].x, rk[0].y); pk0.y = cvtpk(rk[0].z, rk[0].w);
      pk0.z = cvtpk(rk[1].x, rk[1].y); pk0.w = cvtpk(rk[1].z, rk[1].w);
      pk1.x = cvtpk(rk[2].x, rk[2].y); pk1.y = cvtpk(rk[2].z, rk[2].w);
      pk1.z = cvtpk(rk[3].x, rk[3].y); pk1.w = cvtpk(rk[3].z, rk[3].w);
      int dcs0 = (dblk & 8) | ((dblk ^ tq) & 7);
      int dcs1 = (dblk & 8) | ((dblk ^ (tq + 1)) & 7);
      *(uint4*)(&Ks[buf][tq * 128 + dcs0 * 8])       = pk0;
      *(uint4*)(&Ks[buf][(tq + 1) * 128 + dcs1 * 8]) = pk1;
      float va[8] = {rv[0].x, rv[0].y, rv[0].z, rv[0].w, rv[1].x, rv[1].y, rv[1].z, rv[1].w};
      float vb[8] = {rv[2].x, rv[2].y, rv[2].z, rv[2].w, rv[3].x, rv[3].y, rv[3].z, rv[3].w};
      #pragma unroll
      for (int dd = 0; dd < 8; ++dd){
        int d = dblk * 8 + dd;
        int cc = (p ^ ((dblk ^ dd) & 3) ^ (dblk >> 2)) & 3;   // chunk=p, swz ((d>>3)^d)&3 ^ (d>>5)
        *(u32*)(&Vs[buf][d * 36 + cc * 8 + lh * 2]) = cvtpk(va[dd], vb[dd]);
      }
    };

    float4 rkA[4], rvA[4], rkB[4], rvB[4];
    loadTile(0, rkA, rvA);
    asm volatile("s_waitcnt vmcnt(0)" ::: "memory");
    writeTile(0, rkA, rvA);
    loadTile(1, rkB, rvB);
    asm volatile("s_waitcnt lgkmcnt(0)" ::: "memory");
    __builtin_amdgcn_sched_barrier(0);
    __builtin_amdgcn_s_barrier();
    __builtin_amdgcn_sched_barrier(0);
    for (int it = 0; it < NT; it += 2){
      // consumer on buf0 (tile it); stage tile it+1 -> buf1 from B; prefetch it+2 -> A
      if (it + 1 < NT){
        asm volatile("s_waitcnt vmcnt(0)" ::: "memory");
        writeTile(1, rkB, rvB);
        if (it + 2 < NT) loadTile(it + 2, rkA, rvA);
        asm volatile("s_waitcnt lgkmcnt(0)" ::: "memory");
      }
      __builtin_amdgcn_sched_barrier(0);
      __builtin_amdgcn_s_barrier();
      __builtin_amdgcn_sched_barrier(0);
      // consumer on buf1 (tile it+1); stage tile it+2 -> buf0 from A; prefetch it+3 -> B
      if (it + 2 < NT){
        asm volatile("s_waitcnt vmcnt(0)" ::: "memory");
        writeTile(0, rkA, rvA);
        if (it + 3 < NT) loadTile(it + 3, rkB, rvB);
        asm volatile("s_waitcnt lgkmcnt(0)" ::: "memory");
      }
      __builtin_amdgcn_sched_barrier(0);
      __builtin_amdgcn_s_barrier();
      __builtin_amdgcn_sched_barrier(0);
    }
    return;
  }

  // ================= consumer =================
  // stage own Q (pre-swizzled in qrope -> linear copy keeps swizzle)
  const u16* qb = qrope + (size_t)((b * 32 + kv * 4 + w) * 64) * 128;
  #pragma unroll
  for (int c = 0; c < 16; ++c)
    llds16((const char*)qb + c * 1024 + lane * 16, (char*)(&Qs[w][0]) + c * 1024);
  asm volatile("s_waitcnt vmcnt(0)" ::: "memory");

  f32x4 cacc[8][4];             // [nd][qm]: ctx^T rows d=nd*16+lh*4+r, cols q=qm*16+l15
  float mrow[4], lrow[4];
  #pragma unroll
  for (int qm = 0; qm < 4; ++qm){ mrow[qm] = -3.0e38f; lrow[qm] = 0.f; }
  #pragma unroll
  for (int nd = 0; nd < 8; ++nd)
    #pragma unroll
    for (int qm = 0; qm < 4; ++qm) cacc[nd][qm] = f32x4{0.f, 0.f, 0.f, 0.f};

  __builtin_amdgcn_sched_barrier(0);
  __builtin_amdgcn_s_barrier();
  __builtin_amdgcn_sched_barrier(0);

  for (int it = 0; it < NT; ++it){
    const u16* Kc = &Ks[it & 1][0];
    const u16* Vc = &Vs[it & 1][0];

    // S^T = K * Q^T : sacc[tt][qm] rows t=tt*16+lh*4+r, cols q=qm*16+l15
    f32x4 sacc[2][4];
    #pragma unroll
    for (int tt = 0; tt < 2; ++tt)
      #pragma unroll
      for (int qm = 0; qm < 4; ++qm) sacc[tt][qm] = f32x4{0.f, 0.f, 0.f, 0.f};
    #pragma unroll
    for (int ks = 0; ks < 4; ++ks){
      int dc = ks * 4 + lh;
      int dcs = (dc & 8) | ((dc ^ l15) & 7);
      uint4 kf0 = *(const uint4*)(Kc + l15 * 128 + dcs * 8);
      uint4 kf1 = *(const uint4*)(Kc + (16 + l15) * 128 + dcs * 8);
      #pragma unroll
      for (int qm = 0; qm < 4; ++qm){
        uint4 qf = *(const uint4*)(&Qs[w][(qm * 16 + l15) * 128 + dcs * 8]);
        sacc[0][qm] = __builtin_amdgcn_mfma_f32_16x16x32_bf16(as_bf(kf0), as_bf(qf), sacc[0][qm], 0, 0, 0);
        sacc[1][qm] = __builtin_amdgcn_mfma_f32_16x16x32_bf16(as_bf(kf1), as_bf(qf), sacc[1][qm], 0, 0, 0);
      }
    }

    // causal mask: only last two tiles of chunk 1 (new tokens start at t=4032)
    if (chunk == 1 && it >= 62){
      int toff = (it - 62) * 32;
      #pragma unroll
      for (int tt = 0; tt < 2; ++tt)
        #pragma unroll
        for (int qm = 0; qm < 4; ++qm)
          #pragma unroll
          for (int r = 0; r < 4; ++r){
            int t = toff + tt * 16 + lh * 4 + r;
            int q = qm * 16 + l15;
            if (t > q) sacc[tt][qm][r] = -3.0e38f;
          }
    }

    // lazy online softmax: lane-local max check; full reduce+rescale only on trigger;
    // l kept as lane-local partial (sum is linear) and reduced once after the loop.
    #pragma unroll
    for (int qm = 0; qm < 4; ++qm){
      float rm = sacc[0][qm][0];
      #pragma unroll
      for (int tt = 0; tt < 2; ++tt)
        #pragma unroll
        for (int r = 0; r < 4; ++r) rm = fmaxf(rm, sacc[tt][qm][r]);
      if (__any(rm > mrow[qm] + 8.0f)){          // defer-max (log2 units)
        rm = fmaxf(rm, __shfl_xor(rm, 16));
        rm = fmaxf(rm, __shfl_xor(rm, 32));
        float mn = fmaxf(mrow[qm], rm);
        float esc = exp2f(mrow[qm] - mn);
        mrow[qm] = mn;
        lrow[qm] *= esc;
        #pragma unroll
        for (int nd = 0; nd < 8; ++nd) cacc[nd][qm] *= esc;
      }
      float s = 0.f;
      #pragma unroll
      for (int tt = 0; tt < 2; ++tt)
        #pragma unroll
        for (int r = 0; r < 4; ++r){
          float pp = exp2f(sacc[tt][qm][r] - mrow[qm]);
          sacc[tt][qm][r] = pp;
          s += pp;
        }
      lrow[qm] += s;                             // lane-local partial
    }

    // ctx^T += V^T * P^T via 16x16x16 MFMA (P in registers)
    #pragma unroll
    for (int tt = 0; tt < 2; ++tt){
      s16x4 pa[4];
      #pragma unroll
      for (int qm = 0; qm < 4; ++qm){
        uint2 u;
        u.x = cvtpk(sacc[tt][qm][0], sacc[tt][qm][1]);
        u.y = cvtpk(sacc[tt][qm][2], sacc[tt][qm][3]);
        pa[qm] = __builtin_bit_cast(s16x4, u);
      }
      #pragma unroll
      for (int nd = 0; nd < 8; ++nd){
        int swzv = ((nd * 2) ^ (l15 >> 3) ^ l15) & 3;          // ((d>>3)^d)&3
        int cc = ((tt * 2 + (lh >> 1)) ^ swzv ^ (nd >> 1)) & 3;
        uint2 vr = *(const uint2*)(Vc + (nd * 16 + l15) * 36 + cc * 8 + (lh & 1) * 4);
        s16x4 vfr = __builtin_bit_cast(s16x4, vr);
        #pragma unroll
        for (int qm = 0; qm < 4; ++qm)
          cacc[nd][qm] = mfma16(vfr, pa[qm], cacc[nd][qm]);
      }
    }
    __builtin_amdgcn_sched_barrier(0);
    __builtin_amdgcn_s_barrier();
    __builtin_amdgcn_sched_barrier(0);
  }

  // reduce lane-local l partials across the 4 lh replicas of each q
  #pragma unroll
  for (int qm = 0; qm < 4; ++qm){
    lrow[qm] += __shfl_xor(lrow[qm], 16);
    lrow[qm] += __shfl_xor(lrow[qm], 32);
  }

  // unnormalized partials as bf16 (contiguous 8-B stores) + (m,l)
  u16* pc = pctx + (size_t)(((chunk * 16 + b) * 8 + kv) * 4 + w) * 8192;
  #pragma unroll
  for (int qm = 0; qm < 4; ++qm){
    int q = qm * 16 + l15;
    #pragma unroll
    for (int nd = 0; nd < 8; ++nd){
      uint2 u;
      u.x = cvtpk(cacc[nd][qm][0], cacc[nd][qm][1]);
      u.y = cvtpk(cacc[nd][qm][2], cacc[nd][qm][3]);
      *(uint2*)(pc + (size_t)q * 128 + nd * 16 + lh * 4) = u;
    }
  }
  if (lh == 0){
    size_t mb = (size_t)((chunk * 16 + b) * 8 + kv) * 256 + w * 64;
    #pragma unroll
    for (int qm = 0; qm < 4; ++qm){
      pm[mb + qm * 16 + l15] = mrow[qm];
      pl[mb + qm * 16 + l15] = lrow[qm];
    }
  }
}

// ---------------- combine the 2 chunk partials (bf16 partials, uint4-vectorized) ----------------
__global__ __launch_bounds__(256) void combine_kernel(const u16* __restrict__ pctx, const float* __restrict__ pm,
                                                      const float* __restrict__ pl, u16* __restrict__ ctxb){
  int z = blockIdx.x;
  int g = z & 3, kv = (z >> 2) & 7, b = z >> 5;
  int tid = threadIdx.x;
  int s = tid >> 2, dq = (tid & 3) * 32;
  float mv[2], lv[2];
  #pragma unroll
  for (int c = 0; c < 2; ++c){
    size_t mi = (size_t)((c * 16 + b) * 8 + kv) * 256 + g * 64 + s;
    mv[c] = pm[mi]; lv[c] = pl[mi];
  }
  float M = fmaxf(mv[0], mv[1]);
  float wc[2], wsum = 0.f;
  #pragma unroll
  for (int c = 0; c < 2; ++c){ wc[c] = exp2f(mv[c] - M); wsum += wc[c] * lv[c]; }
  float inv = 1.0f / wsum;
  u16* dst = ctxb + (size_t)(b * 64 + s) * 4096 + (kv * 4 + g) * 128 + dq;
  #pragma unroll
  for (int j8 = 0; j8 < 4; ++j8){                // 8 bf16 per iteration
    float a[8] = {0.f, 0.f, 0.f, 0.f, 0.f, 0.f, 0.f, 0.f};
    #pragma unroll
    for (int c = 0; c < 2; ++c){
      const u16* p = pctx + (size_t)(((c * 16 + b) * 8 + kv) * 4 + g) * 8192 + s * 128 + dq + j8 * 8;
      uint4 v = *(const uint4*)p;
      u16 e[8]; *(uint4*)e = v;
      #pragma unroll
      for (int k = 0; k < 8; ++k) a[k] += wc[c] * bf2f(e[k]);
    }
    u16 t8[8];
    #pragma unroll
    for (int k = 0; k < 8; ++k) t8[k] = f2bf(a[k] * inv);
    *(uint4*)(dst + j8 * 8) = *(const uint4*)t8;
  }
}

extern "C" void kernel_launch(void* const* d_in, const int* in_sizes, int n_in,
                              void* d_out, int out_size, void* d_ws, size_t ws_size,
                              hipStream_t stream){
  const float* hidden = (const float*)d_in[0];
  const float* pastk  = (const float*)d_in[1];
  const float* pastv  = (const float*)d_in[2];
  const float* qw     = (const float*)d_in[3];
  const float* kw     = (const float*)d_in[4];
  const float* vw     = (const float*)d_in[5];
  const float* ow     = (const float*)d_in[6];
  const int*   beam   = (const int*)d_in[7];

  char* ws = (char*)d_ws;
  size_t off = 0;
  auto alloc = [&](size_t sz){ char* p = ws + off; off += sz; return p; };
  u16*   wtall = (u16*)alloc(50331648);     // [6144][4096] bf16: q,k,v weights transposed
  u16*   wto   = (u16*)alloc(33554432);     // [4096][4096] bf16: out_wei transposed
  u16*   hidb  = (u16*)alloc(8388608);      // hidden bf16 [1024][4096]
  u16*   qkvp  = (u16*)alloc(12582912);     // QKV proj [1024][6144]
  u16*   qrope = (u16*)alloc(8388608);      // [16][32][64][128] swizzled
  float* knew  = (float*)alloc(4194304);    // [16][8][64][128] fp32 roped new K
  float* vnew  = (float*)alloc(4194304);    // [16][8][64][128] fp32 new V
  u16*   pctx  = (u16*)alloc(16777216);     // [2][16][8][4][64][128] bf16 partials
  float* pm    = (float*)alloc(262144);
  float* pl    = (float*)alloc(262144);
  u16*   ctxb  = (u16*)alloc(8388608);      // [1024][4096]
  float2* tbl  = (float2*)alloc(32768);     // [64 s][64 j] cos/sin
  if (off > ws_size) return;                // workspace too small -> fail loudly

  cvt_hid_kernel<<<2064, 256, 0, stream>>>(hidden, hidb, tbl);
  wtrans_kernel<<<10240, 256, 0, stream>>>(qw, kw, vw, ow, wtall, wto);
  gemm_kernel<0><<<768, 256, 0, stream>>>(hidb, wtall, (void*)qkvp, 6144, 96);
  rope_kernel<<<640, 256, 0, stream>>>(qkvp, tbl, qrope, knew, vnew);
  attn_kernel<<<dim3(8, 16, 2), 512, 0, stream>>>(qrope, pastk, pastv, knew, vnew, beam, pctx, pm, pl);
  combine_kernel<<<512, 256, 0, stream>>>(pctx, pm, pl, ctxb);
  gemm_kernel<1><<<512, 256, 0, stream>>>(ctxb, wto, d_out, 4096, 64);
}